// Round 1
// baseline (4002.577 us; speedup 1.0000x reference)
//
#include <hip/hip_runtime.h>
#include <cmath>

// ---------------------------------------------------------------------------
// Tconv_35450660061268 : full model implementation.
// Key algebraic rewrite: _tconv(e, mmt) == e @ M(v)^T + tc_pb with
//   v = mmt @ tc_w^T + tc_b,  M[o,p] = sum_{k,i,j: j+i=p} tc_pw[o,k*97+j]*v[k,i]
// so every timestep's TemporalConv is a 128x128 linear map (built once per t).
//
// Memory plan:
//   d_out (41,222,144 f32 = 165 MB) is used as scratch for 4 rotating NE*H
//   buffers (82 MB) during the t-loop; logits are written only at the end,
//   reading exclusively from d_ws-resident data (final ent/relh, Z, etc.).
//   d_ws usage: ~23.9 MB.
// ---------------------------------------------------------------------------

namespace {

constexpr int H   = 128;
constexpr int KK  = 4;
constexpr int C   = 32;
constexpr int NE  = 40000;
constexpr int NR  = 256;
constexpr int T   = 4;
constexpr int E   = 100000;
constexpr int NT  = 1024;
constexpr int PIN = 388;     // H*KK - H + KK
constexpr int MW  = 1280;    // mask words per relation (padded; 1250 used)
constexpr int MWU = 1250;    // ceil(NE/32) == 40000/32 exactly
constexpr size_t NEH = (size_t)NE * H;

__device__ __forceinline__ float sigm(float x) { return 1.0f / (1.0f + expf(-x)); }

// ---- row L2-normalize (works in-place), one wave per row -------------------
__global__ __launch_bounds__(256) void norm_rows(const float* __restrict__ in,
                                                 float* __restrict__ out, int n) {
  int row  = blockIdx.x * 4 + (threadIdx.x >> 6);
  int lane = threadIdx.x & 63;
  if (row >= n) return;
  const float2* ip = reinterpret_cast<const float2*>(in + (size_t)row * H);
  float2 v = ip[lane];
  float ss = v.x * v.x + v.y * v.y;
#pragma unroll
  for (int off = 32; off; off >>= 1) ss += __shfl_xor(ss, off);
  float inv = 1.0f / fmaxf(sqrtf(ss), 1e-12f);
  float2 o; o.x = v.x * inv; o.y = v.y * inv;
  reinterpret_cast<float2*>(out + (size_t)row * H)[lane] = o;
}

__global__ void copy_vec(const float* __restrict__ a, float* __restrict__ b, int n) {
  int i = blockIdx.x * blockDim.x + threadIdx.x;
  if (i < n) b[i] = a[i];
}

// ---- mmt GRU pair + gated update + v = mmt_new @ tc_w^T + tc_b (1 block) ---
__global__ __launch_bounds__(128) void mmt_step(
    const float* __restrict__ mmt_in,
    const float* __restrict__ w1, const float* __restrict__ bi1, const float* __restrict__ bh1,
    const float* __restrict__ w2, const float* __restrict__ bi2, const float* __restrict__ bh2,
    const float* __restrict__ tcw, const float* __restrict__ tcb,
    float* __restrict__ mmt_out, float* __restrict__ vout) {
  __shared__ float sm[H], sm2[H];
  int t = threadIdx.x;
  sm[t] = mmt_in[t];
  __syncthreads();
  float g1r = bi1[t], g1z = bi1[H + t], g1n = bi1[2 * H + t];
  float g2r = bi2[t], g2z = bi2[H + t], g2n = bi2[2 * H + t];
  for (int k = 0; k < H; k++) {
    float x = sm[k];
    g1r += x * w1[t * H + k];
    g1z += x * w1[(H + t) * H + k];
    g1n += x * w1[(2 * H + t) * H + k];
    g2r += x * w2[t * H + k];
    g2z += x * w2[(H + t) * H + k];
    g2n += x * w2[(2 * H + t) * H + k];
  }
  // h = 0 => gh = bhh
  float r1 = sigm(g1r + bh1[t]), z1 = sigm(g1z + bh1[H + t]);
  float n1 = tanhf(g1n + r1 * bh1[2 * H + t]);
  float nmmt = (1.0f - z1) * n1;
  float r2 = sigm(g2r + bh2[t]), z2 = sigm(g2z + bh2[H + t]);
  float n2 = tanhf(g2n + r2 * bh2[2 * H + t]);
  float gg = (1.0f - z2) * n2;
  float m  = sm[t];
  float mo = m + gg * (nmmt - m);
  mmt_out[t] = mo;
  sm2[t] = mo;
  __syncthreads();
  float v = tcb[t];
  for (int k = 0; k < H; k++) v += sm2[k] * tcw[t * H + k];
  vout[t] = v;
}

// ---- build MT[p*H+o] = M[o][p] from v and tc_pw ----------------------------
__global__ __launch_bounds__(128) void build_M(const float* __restrict__ v,
                                               const float* __restrict__ pw,
                                               float* __restrict__ MT) {
  int o = blockIdx.x, p = threadIdx.x;
  __shared__ float sp[PIN];
  __shared__ float sv[H];
  for (int i = p; i < PIN; i += H) sp[i] = pw[(size_t)o * PIN + i];
  sv[p] = v[p];
  __syncthreads();
  float acc = 0.0f;
  int jlo = p - 31 > 0 ? p - 31 : 0;
  int jhi = p < 96 ? p : 96;
#pragma unroll
  for (int k = 0; k < KK; k++)
    for (int j = jlo; j <= jhi; j++) acc += sp[k * 97 + j] * sv[k * 32 + (p - j)];
  MT[p * H + o] = acc;
}

// ---- generic linear kernels: weights [k][o] staged in 64KB LDS -------------
// 256 thr = 4 groups of 64 lanes; group handles 4 nodes; lane owns dims (l, l+64).
// n must be a multiple of 16 (NE=40000, NR=256 both are).

__global__ __launch_bounds__(256) void lin_plain(const float* __restrict__ in,
                                                 const float* __restrict__ WT,
                                                 const float* __restrict__ bias,
                                                 float* __restrict__ out, int n) {
  __shared__ float sW[H * H];
  int tid = threadIdx.x;
  for (int i = tid; i < H * H; i += 256) sW[i] = WT[i];
  __syncthreads();
  int lane = tid & 63, g = tid >> 6;
  float blo = bias[lane], bhi = bias[lane + 64];
  for (int base = blockIdx.x * 16; base < n; base += gridDim.x * 16) {
    const float* p0 = in + (size_t)(base + g * 4) * H;
    float a0l = 0, a0h = 0, a1l = 0, a1h = 0, a2l = 0, a2h = 0, a3l = 0, a3h = 0;
#pragma unroll 4
    for (int k = 0; k < H; k++) {
      float wl = sW[k * H + lane], wh = sW[k * H + 64 + lane];
      float x0 = p0[k], x1 = p0[H + k], x2 = p0[2 * H + k], x3 = p0[3 * H + k];
      a0l += x0 * wl; a0h += x0 * wh;
      a1l += x1 * wl; a1h += x1 * wh;
      a2l += x2 * wl; a2h += x2 * wh;
      a3l += x3 * wl; a3h += x3 * wh;
    }
    float* q = out + (size_t)(base + g * 4) * H;
    q[lane] = a0l + blo;           q[64 + lane] = a0h + bhi;
    q[H + lane] = a1l + blo;       q[H + 64 + lane] = a1h + bhi;
    q[2 * H + lane] = a2l + blo;   q[2 * H + 64 + lane] = a2h + bhi;
    q[3 * H + lane] = a3l + blo;   q[3 * H + 64 + lane] = a3h + bhi;
  }
}

// tmp = (agg/max(cnt,1)) @ WT  (scale folded out of the k-loop: linear)
__global__ __launch_bounds__(256) void lin_scaled(const float* __restrict__ agg,
                                                  const float* __restrict__ WT,
                                                  const float* __restrict__ cnt,
                                                  float* __restrict__ out, int n) {
  __shared__ float sW[H * H];
  int tid = threadIdx.x;
  for (int i = tid; i < H * H; i += 256) sW[i] = WT[i];
  __syncthreads();
  int lane = tid & 63, g = tid >> 6;
  for (int base = blockIdx.x * 16; base < n; base += gridDim.x * 16) {
    int r0 = base + g * 4;
    const float* p0 = agg + (size_t)r0 * H;
    float i0 = 1.0f / fmaxf(cnt[r0], 1.0f);
    float i1 = 1.0f / fmaxf(cnt[r0 + 1], 1.0f);
    float i2 = 1.0f / fmaxf(cnt[r0 + 2], 1.0f);
    float i3 = 1.0f / fmaxf(cnt[r0 + 3], 1.0f);
    float a0l = 0, a0h = 0, a1l = 0, a1h = 0, a2l = 0, a2h = 0, a3l = 0, a3h = 0;
#pragma unroll 4
    for (int k = 0; k < H; k++) {
      float wl = sW[k * H + lane], wh = sW[k * H + 64 + lane];
      float x0 = p0[k], x1 = p0[H + k], x2 = p0[2 * H + k], x3 = p0[3 * H + k];
      a0l += x0 * wl; a0h += x0 * wh;
      a1l += x1 * wl; a1h += x1 * wh;
      a2l += x2 * wl; a2h += x2 * wh;
      a3l += x3 * wl; a3h += x3 * wh;
    }
    float* q = out + (size_t)r0 * H;
    q[lane] = a0l * i0;           q[64 + lane] = a0h * i0;
    q[H + lane] = a1l * i1;       q[H + 64 + lane] = a1h * i1;
    q[2 * H + lane] = a2l * i2;   q[2 * H + 64 + lane] = a2h * i2;
    q[3 * H + lane] = a3l * i3;   q[3 * H + 64 + lane] = a3h * i3;
  }
}

// out = relu(tmp + h @ WT + b)
__global__ __launch_bounds__(256) void lin_addrelu(const float* __restrict__ hmat,
                                                   const float* __restrict__ WT,
                                                   const float* __restrict__ tmp,
                                                   const float* __restrict__ bias,
                                                   float* __restrict__ out, int n) {
  __shared__ float sW[H * H];
  int tid = threadIdx.x;
  for (int i = tid; i < H * H; i += 256) sW[i] = WT[i];
  __syncthreads();
  int lane = tid & 63, g = tid >> 6;
  float blo = bias[lane], bhi = bias[lane + 64];
  for (int base = blockIdx.x * 16; base < n; base += gridDim.x * 16) {
    int r0 = base + g * 4;
    const float* p0 = hmat + (size_t)r0 * H;
    float a0l = 0, a0h = 0, a1l = 0, a1h = 0, a2l = 0, a2h = 0, a3l = 0, a3h = 0;
#pragma unroll 4
    for (int k = 0; k < H; k++) {
      float wl = sW[k * H + lane], wh = sW[k * H + 64 + lane];
      float x0 = p0[k], x1 = p0[H + k], x2 = p0[2 * H + k], x3 = p0[3 * H + k];
      a0l += x0 * wl; a0h += x0 * wh;
      a1l += x1 * wl; a1h += x1 * wh;
      a2l += x2 * wl; a2h += x2 * wh;
      a3l += x3 * wl; a3h += x3 * wh;
    }
    const float* tp = tmp + (size_t)r0 * H;
    float* q = out + (size_t)r0 * H;
    q[lane]            = fmaxf(tp[lane] + a0l + blo, 0.0f);
    q[64 + lane]       = fmaxf(tp[64 + lane] + a0h + bhi, 0.0f);
    q[H + lane]        = fmaxf(tp[H + lane] + a1l + blo, 0.0f);
    q[H + 64 + lane]   = fmaxf(tp[H + 64 + lane] + a1h + bhi, 0.0f);
    q[2*H + lane]      = fmaxf(tp[2*H + lane] + a2l + blo, 0.0f);
    q[2*H + 64 + lane] = fmaxf(tp[2*H + 64 + lane] + a2h + bhi, 0.0f);
    q[3*H + lane]      = fmaxf(tp[3*H + lane] + a3l + blo, 0.0f);
    q[3*H + 64 + lane] = fmaxf(tp[3*H + 64 + lane] + a3h + bhi, 0.0f);
  }
}

// u = sigmoid(ent @ lin_w^T + lin_b); out = ent + u*(nf - ent)
__global__ __launch_bounds__(256) void lin_update(const float* __restrict__ ent,
                                                  const float* __restrict__ linw,
                                                  const float* __restrict__ linb,
                                                  const float* __restrict__ nf,
                                                  float* __restrict__ out, int n) {
  __shared__ float sW[H * H];
  int tid = threadIdx.x;
  // transpose lin_w (o-major) into sW[k][o]; conflict-free LDS writes
  for (int i = tid; i < H * H; i += 256) {
    int kk = i >> 7, oo = i & 127;
    sW[kk * H + oo] = linw[(size_t)oo * H + kk];
  }
  __syncthreads();
  int lane = tid & 63, g = tid >> 6;
  float blo = linb[lane], bhi = linb[lane + 64];
  for (int base = blockIdx.x * 16; base < n; base += gridDim.x * 16) {
    int r0 = base + g * 4;
    const float* p0 = ent + (size_t)r0 * H;
    float a0l = 0, a0h = 0, a1l = 0, a1h = 0, a2l = 0, a2h = 0, a3l = 0, a3h = 0;
#pragma unroll 4
    for (int k = 0; k < H; k++) {
      float wl = sW[k * H + lane], wh = sW[k * H + 64 + lane];
      float x0 = p0[k], x1 = p0[H + k], x2 = p0[2 * H + k], x3 = p0[3 * H + k];
      a0l += x0 * wl; a0h += x0 * wh;
      a1l += x1 * wl; a1h += x1 * wh;
      a2l += x2 * wl; a2h += x2 * wh;
      a3l += x3 * wl; a3h += x3 * wh;
    }
    const float* fp = nf + (size_t)r0 * H;
    float* q = out + (size_t)r0 * H;
#pragma unroll
    for (int m = 0; m < 4; m++) {
      float al = (m == 0 ? a0l : m == 1 ? a1l : m == 2 ? a2l : a3l);
      float ah = (m == 0 ? a0h : m == 1 ? a1h : m == 2 ? a2h : a3h);
      float ul = sigm(al + blo), uh = sigm(ah + bhi);
      float el = p0[m * H + lane], eh = p0[m * H + 64 + lane];
      float fl = fp[m * H + lane], fh = fp[m * H + 64 + lane];
      q[m * H + lane]      = el + ul * (fl - el);
      q[m * H + 64 + lane] = eh + uh * (fh - eh);
    }
  }
}

// ---- _agg_rel: bitmask scatter + masked mean -------------------------------
__global__ __launch_bounds__(256) void mask_scatter(const int* __restrict__ s,
                                                    const int* __restrict__ d,
                                                    const int* __restrict__ r,
                                                    unsigned int* __restrict__ mask) {
  int e = blockIdx.x * 256 + threadIdx.x;
  if (e >= E) return;
  int ri = r[e], si = s[e], di = d[e];
  atomicOr(&mask[(size_t)ri * MW + (si >> 5)], 1u << (si & 31));
  atomicOr(&mask[(size_t)ri * MW + (di >> 5)], 1u << (di & 31));
}

__global__ __launch_bounds__(128) void agg_rel_sum(const unsigned int* __restrict__ mask,
                                                   const float* __restrict__ ent,
                                                   float* __restrict__ rsum,
                                                   float* __restrict__ rcnt) {
  int rel = blockIdx.x, part = blockIdx.y, tid = threadIdx.x;
  const int WPS = (MWU + 7) / 8;  // 157
  int w0 = part * WPS;
  int w1 = w0 + WPS < MWU ? w0 + WPS : MWU;
  float acc = 0.0f, cnt = 0.0f;
  const unsigned int* mrow = mask + (size_t)rel * MW;
  for (int w = w0; w < w1; w++) {
    unsigned int bits = mrow[w];
    if (!bits) continue;
    cnt += (float)__popc(bits);
    int base = w << 5;
    while (bits) {
      int b = __ffs(bits) - 1;
      bits &= bits - 1;
      acc += ent[(size_t)(base + b) * H + tid];
    }
  }
  atomicAdd(&rsum[rel * H + tid], acc);
  if (tid == 0) atomicAdd(&rcnt[rel], cnt);
}

__global__ __launch_bounds__(256) void rel_finalize(const float* __restrict__ rs,
                                                    const float* __restrict__ rc,
                                                    float* __restrict__ re) {
  int i = blockIdx.x * 256 + threadIdx.x;
  if (i >= NR * H) return;
  float c = rc[i >> 7];
  re[i] = c > 0.0f ? rs[i] / fmaxf(c, 1.0f) : 0.0f;
}

// ---- relation GRU (+ row normalize), one block per relation ----------------
__global__ __launch_bounds__(128) void rel_gru(const float* __restrict__ rel_ent,
                                               const float* __restrict__ rel_param,
                                               const float* __restrict__ relh,
                                               const float* __restrict__ wih,
                                               const float* __restrict__ whh,
                                               const float* __restrict__ bih,
                                               const float* __restrict__ bhh,
                                               float* __restrict__ outp) {
  int rel = blockIdx.x, tid = threadIdx.x;
  __shared__ float sx[2 * H], sh[H], red[H];
  sx[tid]     = rel_ent[rel * H + tid];
  sx[H + tid] = rel_param[rel * H + tid];
  sh[tid]     = relh[rel * H + tid];
  __syncthreads();
  float gr = bih[tid], gz = bih[H + tid], gn = bih[2 * H + tid];
  for (int k = 0; k < 2 * H; k++) {
    float x = sx[k];
    gr += x * wih[(size_t)tid * 2 * H + k];
    gz += x * wih[(size_t)(H + tid) * 2 * H + k];
    gn += x * wih[(size_t)(2 * H + tid) * 2 * H + k];
  }
  float hr = bhh[tid], hz = bhh[H + tid], hn = bhh[2 * H + tid];
  for (int k = 0; k < H; k++) {
    float hv = sh[k];
    hr += hv * whh[tid * H + k];
    hz += hv * whh[(H + tid) * H + k];
    hn += hv * whh[(2 * H + tid) * H + k];
  }
  float r = sigm(gr + hr), z = sigm(gz + hz), nn = tanhf(gn + r * hn);
  float val = (1.0f - z) * nn + z * sh[tid];
  red[tid] = val * val;
  __syncthreads();
  for (int s2 = 64; s2 > 0; s2 >>= 1) {
    if (tid < s2) red[tid] += red[tid + s2];
    __syncthreads();
  }
  float inv = 1.0f / fmaxf(sqrtf(red[0]), 1e-12f);
  outp[rel * H + tid] = val * inv;
}

// ---- RGCN message scatter: agg[d] += h[s] + nrel[r]; cnt[d] += 1 -----------
__global__ __launch_bounds__(256) void rgcn_scatter(const float* __restrict__ h,
                                                    const float* __restrict__ ef,
                                                    const int* __restrict__ s,
                                                    const int* __restrict__ d,
                                                    const int* __restrict__ r,
                                                    float* __restrict__ agg,
                                                    float* __restrict__ cnt) {
  int idx = blockIdx.x * 256 + threadIdx.x;
  if (idx >= E * 32) return;
  int e = idx >> 5;
  int qd = (idx & 31) << 2;
  int si = s[e], di = d[e], ri = r[e];
  const float4 hv = *reinterpret_cast<const float4*>(&h[(size_t)si * H + qd]);
  const float4 ev = *reinterpret_cast<const float4*>(&ef[(size_t)ri * H + qd]);
  float* a = &agg[(size_t)di * H + qd];
  atomicAdd(a + 0, hv.x + ev.x);
  atomicAdd(a + 1, hv.y + ev.y);
  atomicAdd(a + 2, hv.z + ev.z);
  atomicAdd(a + 3, hv.w + ev.w);
  if (qd == 0) atomicAdd(&cnt[di], 1.0f);
}

// ---- ConvTransE front: Z = relu(relu(conv1d(x)) @ fw^T + fb), 4 queries/blk
__global__ __launch_bounds__(256) void conv_front(const float* __restrict__ fa,
                                                  const int* __restrict__ ia,
                                                  const float* __restrict__ fbm,
                                                  const int* __restrict__ ib,
                                                  const float* __restrict__ ck,
                                                  const float* __restrict__ ckb,
                                                  const float* __restrict__ fw,
                                                  const float* __restrict__ fbias,
                                                  float* __restrict__ Z) {
  __shared__ float sy[4 * C * H];  // 64KB
  int q0 = blockIdx.x * 4;
  int tid = threadIdx.x;
  for (int i = tid; i < 4 * C * H; i += 256) {
    int q = i >> 12, c = (i >> 7) & 31, p = i & 127;
    const float* xa = fa + (size_t)ia[q0 + q] * H;
    const float* xb = fbm + (size_t)ib[q0 + q] * H;
    float acc = ckb[c];
#pragma unroll
    for (int kk2 = 0; kk2 < 3; kk2++) {
      int pos = p + kk2 - 1;
      if (pos >= 0 && pos < H)
        acc += xa[pos] * ck[c * 6 + kk2] + xb[pos] * ck[c * 6 + 3 + kk2];
    }
    sy[i] = fmaxf(acc, 0.0f);
  }
  __syncthreads();
  int o = tid & 127, g = tid >> 7;
  float acc0 = fbias[o], acc1 = fbias[o];
  const float* wrow = fw + (size_t)o * (C * H);
  const float* y0 = &sy[(g * 2 + 0) * C * H];
  const float* y1 = &sy[(g * 2 + 1) * C * H];
  for (int j = 0; j < C * H; j += 4) {
    float4 w = *reinterpret_cast<const float4*>(&wrow[j]);
    float4 a = *reinterpret_cast<const float4*>(&y0[j]);
    float4 b = *reinterpret_cast<const float4*>(&y1[j]);
    acc0 += a.x * w.x + a.y * w.y + a.z * w.z + a.w * w.w;
    acc1 += b.x * w.x + b.y * w.y + b.z * w.z + b.w * w.w;
  }
  Z[(size_t)(q0 + g * 2 + 0) * H + o] = fmaxf(acc0, 0.0f);
  Z[(size_t)(q0 + g * 2 + 1) * H + o] = fmaxf(acc1, 0.0f);
}

// ---- logits: out[n,m] = dot(Z[n,:], F[m,:]); 64x64 tile, k-major LDS -------
__global__ __launch_bounds__(256) void logits_gemm(const float* __restrict__ Zq,
                                                   const float* __restrict__ F,
                                                   float* __restrict__ out, int M) {
  __shared__ float sZ[H * 64];
  __shared__ float sF[H * 64];
  int bq = blockIdx.y * 64, bm = blockIdx.x * 64;
  int tid = threadIdx.x;
  for (int i = tid; i < 64 * H; i += 256) {
    int row = i & 63, k = i >> 6;
    sZ[k * 64 + row] = Zq[(size_t)(bq + row) * H + k];
    sF[k * 64 + row] = F[(size_t)(bm + row) * H + k];
  }
  __syncthreads();
  int tx = tid & 15, ty = tid >> 4;
  float acc[4][4] = {};
  for (int k = 0; k < H; k++) {
    float4 a = *reinterpret_cast<const float4*>(&sZ[k * 64 + ty * 4]);
    float4 b = *reinterpret_cast<const float4*>(&sF[k * 64 + tx * 4]);
    acc[0][0] += a.x * b.x; acc[0][1] += a.x * b.y; acc[0][2] += a.x * b.z; acc[0][3] += a.x * b.w;
    acc[1][0] += a.y * b.x; acc[1][1] += a.y * b.y; acc[1][2] += a.y * b.z; acc[1][3] += a.y * b.w;
    acc[2][0] += a.z * b.x; acc[2][1] += a.z * b.y; acc[2][2] += a.z * b.z; acc[2][3] += a.z * b.w;
    acc[3][0] += a.w * b.x; acc[3][1] += a.w * b.y; acc[3][2] += a.w * b.z; acc[3][3] += a.w * b.w;
  }
#pragma unroll
  for (int i = 0; i < 4; i++) {
    float4 o4 = {acc[i][0], acc[i][1], acc[i][2], acc[i][3]};
    *reinterpret_cast<float4*>(&out[(size_t)(bq + ty * 4 + i) * (size_t)M + bm + tx * 4]) = o4;
  }
}

}  // namespace

extern "C" void kernel_launch(void* const* d_in, const int* in_sizes, int n_in,
                              void* d_out, int out_size, void* d_ws, size_t ws_size,
                              hipStream_t stream) {
  (void)in_sizes; (void)n_in; (void)out_size; (void)ws_size;
  const float* ent_embeds = (const float*)d_in[0];
  const float* rel_embeds = (const float*)d_in[1];
  const float* mmt_embed  = (const float*)d_in[2];
  const float* tc_w  = (const float*)d_in[3];
  const float* tc_b  = (const float*)d_in[4];
  const float* tc_pw = (const float*)d_in[5];
  const float* tc_pb = (const float*)d_in[6];
  const float* g1_wih = (const float*)d_in[7];
  const float* g1_whh = (const float*)d_in[8];
  const float* g1_bih = (const float*)d_in[9];
  const float* g1_bhh = (const float*)d_in[10];
  const float* l1_wih = (const float*)d_in[11];
  const float* l1_bih = (const float*)d_in[13];
  const float* l1_bhh = (const float*)d_in[14];
  const float* l2_wih = (const float*)d_in[15];
  const float* l2_bih = (const float*)d_in[17];
  const float* l2_bhh = (const float*)d_in[18];
  const float* lin_w = (const float*)d_in[19];
  const float* lin_b = (const float*)d_in[20];
  const float* rgcn_wn = (const float*)d_in[21];
  const float* rgcn_ws = (const float*)d_in[22];
  const float* rgcn_b  = (const float*)d_in[23];
  const float* oc_k  = (const float*)d_in[24];
  const float* oc_kb = (const float*)d_in[25];
  const float* oc_fw = (const float*)d_in[26];
  const float* oc_fb = (const float*)d_in[27];
  const float* rc_k  = (const float*)d_in[28];
  const float* rc_kb = (const float*)d_in[29];
  const float* rc_fw = (const float*)d_in[30];
  const float* rc_fb = (const float*)d_in[31];
  const int* src  = (const int*)d_in[32];
  const int* dst  = (const int*)d_in[33];
  const int* rid  = (const int*)d_in[34];
  const int* qsub = (const int*)d_in[35];
  const int* qrel = (const int*)d_in[36];
  const int* qobj = (const int*)d_in[37];

  float* out = (float*)d_out;
  float* ws  = (float*)d_ws;

  // ---- d_ws layout (floats) ~23.9 MB total ----
  size_t off = 0;
  float* entF = ws + off; off += NEH;                 // final ent (read by logits)
  float* relhB[3] = {ws + off, ws + off + (size_t)NR * H, ws + off + 2 * (size_t)NR * H};
  off += 3 * (size_t)NR * H;
  float* rel_ent = ws + off; off += (size_t)NR * H;
  float* rel_sum = ws + off; off += (size_t)NR * H;   // rel_sum + rcnt adjacent (one memset)
  float* rcnt    = ws + off; off += NR;
  float* mmtbuf0 = ws + off; off += H;
  float* mmtbuf1 = ws + off; off += H;
  float* vbuf    = ws + off; off += H;
  float* MT      = ws + off; off += (size_t)H * H;
  float* Zo      = ws + off; off += (size_t)NT * H;
  float* Zr      = ws + off; off += (size_t)NT * H;
  float* cnt     = ws + off; off += NE;
  unsigned int* mask = (unsigned int*)(ws + off); off += (size_t)NR * MW;

  // ---- d_out as scratch: 4 rotating NE*H buffers (82 MB of 165 MB) ----
  float* B[4] = {out, out + NEH, out + 2 * NEH, out + 3 * NEH};
  float* mmtb[2] = {mmtbuf0, mmtbuf1};

  // init: ent = norm(ent_embeds); relh = norm(rel_embeds); mmt = mmt_embed
  norm_rows<<<(NE + 3) / 4, 256, 0, stream>>>(ent_embeds, B[0], NE);
  norm_rows<<<(NR + 3) / 4, 256, 0, stream>>>(rel_embeds, relhB[0], NR);
  copy_vec<<<1, 128, 0, stream>>>(mmt_embed, mmtbuf0, H);

  int cur = 0, curRelh = 0;
  for (int t = 0; t < T; t++) {
    int fr[3], fi = 0;
    for (int b = 0; b < 4; b++) if (b != cur) fr[fi++] = b;
    int bX = fr[0], bG = fr[1], bY = fr[2];
    const int* s_t = src + (size_t)t * E;
    const int* d_t = dst + (size_t)t * E;
    const int* r_t = rid + (size_t)t * E;
    float* mmt_in = mmtb[t & 1];
    float* mmt_out = mmtb[(t + 1) & 1];

    // mmt GRU pair + v
    mmt_step<<<1, 128, 0, stream>>>(mmt_in, l1_wih, l1_bih, l1_bhh,
                                    l2_wih, l2_bih, l2_bhh, tc_w, tc_b, mmt_out, vbuf);
    // tconv as linear map
    build_M<<<H, H, 0, stream>>>(vbuf, tc_pw, MT);
    lin_plain<<<512, 256, 0, stream>>>(B[cur], MT, tc_pb, B[bX], NE);      // ent_t
    lin_plain<<<16, 256, 0, stream>>>(relhB[curRelh], MT, tc_pb, relhB[2], NR);

    // _agg_rel on ent_t
    hipMemsetAsync(mask, 0, (size_t)NR * MW * 4, stream);
    mask_scatter<<<(E + 255) / 256, 256, 0, stream>>>(s_t, d_t, r_t, mask);
    hipMemsetAsync(rel_sum, 0, ((size_t)NR * H + NR) * 4, stream);
    agg_rel_sum<<<dim3(NR, 8), 128, 0, stream>>>(mask, B[bX], rel_sum, rcnt);
    rel_finalize<<<(NR * H) / 256, 256, 0, stream>>>(rel_sum, rcnt, rel_ent);

    // relation GRU + normalize -> n_rel
    int nextRelh = 1 - curRelh;
    rel_gru<<<NR, 128, 0, stream>>>(rel_ent, rel_embeds, relhB[2],
                                    g1_wih, g1_whh, g1_bih, g1_bhh, relhB[nextRelh]);

    // RGCN layer 0 (h = ent_t = B[bX])
    hipMemsetAsync(B[bG], 0, NEH * 4, stream);
    hipMemsetAsync(cnt, 0, (size_t)NE * 4, stream);
    rgcn_scatter<<<(E * 32) / 256, 256, 0, stream>>>(B[bX], relhB[nextRelh], s_t, d_t, r_t, B[bG], cnt);
    lin_scaled<<<512, 256, 0, stream>>>(B[bG], rgcn_wn, cnt, B[cur], NE);              // tmp in Z
    lin_addrelu<<<512, 256, 0, stream>>>(B[bX], rgcn_ws, B[cur], rgcn_b, B[bY], NE);   // h1

    // RGCN layer 1 (h = h1 = B[bY])
    hipMemsetAsync(B[bG], 0, NEH * 4, stream);
    hipMemsetAsync(cnt, 0, (size_t)NE * 4, stream);
    rgcn_scatter<<<(E * 32) / 256, 256, 0, stream>>>(B[bY], relhB[nextRelh], s_t, d_t, r_t, B[bG], cnt);
    lin_scaled<<<512, 256, 0, stream>>>(B[bG], rgcn_wn + H * H, cnt, B[cur], NE);
    lin_addrelu<<<512, 256, 0, stream>>>(B[bY], rgcn_ws + H * H, B[cur], rgcn_b + H, B[bG], NE);  // h2

    // nf = norm(h2) in place; ent_{t+1} = ent_t + sigmoid(ent_t W^T + b)*(nf - ent_t)
    norm_rows<<<NE / 4, 256, 0, stream>>>(B[bG], B[bG], NE);
    float* entDst = (t == T - 1) ? entF : B[bY];
    lin_update<<<512, 256, 0, stream>>>(B[bX], lin_w, lin_b, B[bG], entDst, NE);

    cur = bY;
    curRelh = nextRelh;
  }

  float* relhF = relhB[curRelh];

  // ConvTransE fronts
  conv_front<<<NT / 4, 256, 0, stream>>>(entF, qsub, relhF, qrel, oc_k, oc_kb, oc_fw, oc_fb, Zo);
  conv_front<<<NT / 4, 256, 0, stream>>>(entF, qsub, entF, qobj, rc_k, rc_kb, rc_fw, rc_fb, Zr);

  // logits (only writes to d_out; reads only from d_ws)
  logits_gemm<<<dim3(NE / 64, NT / 64), 256, 0, stream>>>(Zo, entF, out, NE);
  logits_gemm<<<dim3(NR / 64, NT / 64), 256, 0, stream>>>(Zr, relhF, out + (size_t)NT * NE, NR);
}

// Round 2
// 2526.688 us; speedup vs baseline: 1.5841x; 1.5841x over previous
//
#include <hip/hip_runtime.h>
#include <cmath>

// ---------------------------------------------------------------------------
// Tconv_35450660061268 — R2: register-tiled fp32 GEMMs + CSR-gather RGCN.
//   * _tconv folded to 128x128 linear map M(v) (built per t).
//   * All NE-scale GEMMs: 32KB LDS X-tile, 4/8-node x 4-out register tiles,
//     weights streamed from global (L1/L2), epilogues fused.
//   * RGCN aggregation: per-t CSR build (hist/scan/fill) + gather; no float
//     atomics, no 20MB memsets.
//   * logits: 128x128 tile, K-chunked 32, 8x8 register tile.
// d_out doubles as scratch: 4 rotating NE*H buffers + CSR ints in the tail.
// ---------------------------------------------------------------------------

namespace {

constexpr int H   = 128;
constexpr int KK  = 4;
constexpr int C   = 32;
constexpr int NE  = 40000;
constexpr int NR  = 256;
constexpr int T   = 4;
constexpr int E   = 100000;
constexpr int NT  = 1024;
constexpr int PIN = 388;     // H*KK - H + KK
constexpr int MW  = 1280;    // mask words per relation (padded; 1250 used)
constexpr int MWU = 1250;
constexpr size_t NEH = (size_t)NE * H;

__device__ __forceinline__ float sigm(float x) { return 1.0f / (1.0f + expf(-x)); }

// ---- row L2-normalize (works in-place), one wave per row -------------------
__global__ __launch_bounds__(256) void norm_rows(const float* __restrict__ in,
                                                 float* __restrict__ out, int n) {
  int row  = blockIdx.x * 4 + (threadIdx.x >> 6);
  int lane = threadIdx.x & 63;
  if (row >= n) return;
  const float2* ip = reinterpret_cast<const float2*>(in + (size_t)row * H);
  float2 v = ip[lane];
  float ss = v.x * v.x + v.y * v.y;
#pragma unroll
  for (int off = 32; off; off >>= 1) ss += __shfl_xor(ss, off);
  float inv = 1.0f / fmaxf(sqrtf(ss), 1e-12f);
  float2 o; o.x = v.x * inv; o.y = v.y * inv;
  reinterpret_cast<float2*>(out + (size_t)row * H)[lane] = o;
}

__global__ void copy_vec(const float* __restrict__ a, float* __restrict__ b, int n) {
  int i = blockIdx.x * blockDim.x + threadIdx.x;
  if (i < n) b[i] = a[i];
}

__global__ __launch_bounds__(256) void transpose128(const float* __restrict__ in,
                                                    float* __restrict__ out) {
  int i = blockIdx.x * 256 + threadIdx.x;   // grid 64
  int o = i >> 7, k = i & 127;
  out[k * H + o] = in[o * H + k];
}

// ---- mmt GRU pair + gated update + v = mmt_new @ tc_w^T + tc_b (1 block) ---
__global__ __launch_bounds__(128) void mmt_step(
    const float* __restrict__ mmt_in,
    const float* __restrict__ w1, const float* __restrict__ bi1, const float* __restrict__ bh1,
    const float* __restrict__ w2, const float* __restrict__ bi2, const float* __restrict__ bh2,
    const float* __restrict__ tcw, const float* __restrict__ tcb,
    float* __restrict__ mmt_out, float* __restrict__ vout) {
  __shared__ float sm[H], sm2[H];
  int t = threadIdx.x;
  sm[t] = mmt_in[t];
  __syncthreads();
  float g1r = bi1[t], g1z = bi1[H + t], g1n = bi1[2 * H + t];
  float g2r = bi2[t], g2z = bi2[H + t], g2n = bi2[2 * H + t];
  for (int k = 0; k < H; k++) {
    float x = sm[k];
    g1r += x * w1[t * H + k];
    g1z += x * w1[(H + t) * H + k];
    g1n += x * w1[(2 * H + t) * H + k];
    g2r += x * w2[t * H + k];
    g2z += x * w2[(H + t) * H + k];
    g2n += x * w2[(2 * H + t) * H + k];
  }
  float r1 = sigm(g1r + bh1[t]), z1 = sigm(g1z + bh1[H + t]);
  float n1 = tanhf(g1n + r1 * bh1[2 * H + t]);
  float nmmt = (1.0f - z1) * n1;
  float r2 = sigm(g2r + bh2[t]), z2 = sigm(g2z + bh2[H + t]);
  float n2 = tanhf(g2n + r2 * bh2[2 * H + t]);
  float gg = (1.0f - z2) * n2;
  float m  = sm[t];
  float mo = m + gg * (nmmt - m);
  mmt_out[t] = mo;
  sm2[t] = mo;
  __syncthreads();
  float v = tcb[t];
  for (int k = 0; k < H; k++) v += sm2[k] * tcw[t * H + k];
  vout[t] = v;
}

// ---- build MT[p*H+o] = M[o][p] (k-major tconv map) -------------------------
__global__ __launch_bounds__(128) void build_M(const float* __restrict__ v,
                                               const float* __restrict__ pw,
                                               float* __restrict__ MT) {
  int o = blockIdx.x, p = threadIdx.x;
  __shared__ float sp[PIN];
  __shared__ float sv[H];
  for (int i = p; i < PIN; i += H) sp[i] = pw[(size_t)o * PIN + i];
  sv[p] = v[p];
  __syncthreads();
  float acc = 0.0f;
  int jlo = p - 31 > 0 ? p - 31 : 0;
  int jhi = p < 96 ? p : 96;
#pragma unroll
  for (int k = 0; k < KK; k++)
    for (int j = jlo; j <= jhi; j++) acc += sp[k * 97 + j] * sv[k * 32 + (p - j)];
  MT[p * H + o] = acc;
}

// ===========================================================================
// Register-tiled GEMM family. X-tile in LDS (32KB), WT (k-major) streamed
// from global. 256 thr: oq=(t&31)*4 output quad, node-group from t>>5.
// ===========================================================================

// out[n][o] = sum_k X[n][k] WT[k][o] + bias[o]   (NB=64, 8 nodes/thread)
__global__ __launch_bounds__(256) void gemm_bias(const float* __restrict__ X,
                                                 const float* __restrict__ WT,
                                                 const float* __restrict__ bias,
                                                 float* __restrict__ out) {
  __shared__ float sX[64 * H];   // 32KB
  int t = threadIdx.x;
  int base = blockIdx.x * 64;
  const float4* gx = reinterpret_cast<const float4*>(X + (size_t)base * H);
  float4* sx4 = reinterpret_cast<float4*>(sX);
#pragma unroll
  for (int i = 0; i < 8; i++) sx4[t + 256 * i] = gx[t + 256 * i];
  __syncthreads();
  int oq = (t & 31) * 4, ng = (t >> 5) * 8;
  float acc[8][4] = {};
  for (int k = 0; k < H; k += 4) {
    float4 w0 = *reinterpret_cast<const float4*>(&WT[(k + 0) * H + oq]);
    float4 w1 = *reinterpret_cast<const float4*>(&WT[(k + 1) * H + oq]);
    float4 w2 = *reinterpret_cast<const float4*>(&WT[(k + 2) * H + oq]);
    float4 w3 = *reinterpret_cast<const float4*>(&WT[(k + 3) * H + oq]);
#pragma unroll
    for (int m = 0; m < 8; m++) {
      float4 x = *reinterpret_cast<const float4*>(&sX[(ng + m) * H + k]);
      acc[m][0] += x.x * w0.x + x.y * w1.x + x.z * w2.x + x.w * w3.x;
      acc[m][1] += x.x * w0.y + x.y * w1.y + x.z * w2.y + x.w * w3.y;
      acc[m][2] += x.x * w0.z + x.y * w1.z + x.z * w2.z + x.w * w3.z;
      acc[m][3] += x.x * w0.w + x.y * w1.w + x.z * w2.w + x.w * w3.w;
    }
  }
  float4 b4 = *reinterpret_cast<const float4*>(&bias[oq]);
#pragma unroll
  for (int m = 0; m < 8; m++) {
    float4 o4 = {acc[m][0] + b4.x, acc[m][1] + b4.y, acc[m][2] + b4.z, acc[m][3] + b4.w};
    *reinterpret_cast<float4*>(&out[(size_t)(base + ng + m) * H + oq]) = o4;
  }
}

// RGCN layer fused: out = relu( (A@wn)*inv_deg + Hm@ws + b )   (NB=32)
__global__ __launch_bounds__(256) void gemm_rgcn(const float* __restrict__ A,
                                                 const float* __restrict__ Hm,
                                                 const float* __restrict__ wn,
                                                 const float* __restrict__ ws,
                                                 const float* __restrict__ bias,
                                                 const int* __restrict__ deg,
                                                 float* __restrict__ out) {
  __shared__ float sA[32 * H];   // 16KB
  __shared__ float sH[32 * H];   // 16KB
  int t = threadIdx.x;
  int base = blockIdx.x * 32;
  const float4* ga = reinterpret_cast<const float4*>(A + (size_t)base * H);
  const float4* gh = reinterpret_cast<const float4*>(Hm + (size_t)base * H);
  float4* sa4 = reinterpret_cast<float4*>(sA);
  float4* sh4 = reinterpret_cast<float4*>(sH);
#pragma unroll
  for (int i = 0; i < 4; i++) { sa4[t + 256 * i] = ga[t + 256 * i]; sh4[t + 256 * i] = gh[t + 256 * i]; }
  __syncthreads();
  int oq = (t & 31) * 4, ng = (t >> 5) * 4;
  float accA[4][4] = {}, accS[4][4] = {};
  for (int k = 0; k < H; k += 4) {
    float4 n0 = *reinterpret_cast<const float4*>(&wn[(k + 0) * H + oq]);
    float4 n1 = *reinterpret_cast<const float4*>(&wn[(k + 1) * H + oq]);
    float4 n2 = *reinterpret_cast<const float4*>(&wn[(k + 2) * H + oq]);
    float4 n3 = *reinterpret_cast<const float4*>(&wn[(k + 3) * H + oq]);
    float4 s0 = *reinterpret_cast<const float4*>(&ws[(k + 0) * H + oq]);
    float4 s1 = *reinterpret_cast<const float4*>(&ws[(k + 1) * H + oq]);
    float4 s2 = *reinterpret_cast<const float4*>(&ws[(k + 2) * H + oq]);
    float4 s3 = *reinterpret_cast<const float4*>(&ws[(k + 3) * H + oq]);
#pragma unroll
    for (int m = 0; m < 4; m++) {
      float4 a = *reinterpret_cast<const float4*>(&sA[(ng + m) * H + k]);
      float4 h = *reinterpret_cast<const float4*>(&sH[(ng + m) * H + k]);
      accA[m][0] += a.x * n0.x + a.y * n1.x + a.z * n2.x + a.w * n3.x;
      accA[m][1] += a.x * n0.y + a.y * n1.y + a.z * n2.y + a.w * n3.y;
      accA[m][2] += a.x * n0.z + a.y * n1.z + a.z * n2.z + a.w * n3.z;
      accA[m][3] += a.x * n0.w + a.y * n1.w + a.z * n2.w + a.w * n3.w;
      accS[m][0] += h.x * s0.x + h.y * s1.x + h.z * s2.x + h.w * s3.x;
      accS[m][1] += h.x * s0.y + h.y * s1.y + h.z * s2.y + h.w * s3.y;
      accS[m][2] += h.x * s0.z + h.y * s1.z + h.z * s2.z + h.w * s3.z;
      accS[m][3] += h.x * s0.w + h.y * s1.w + h.z * s2.w + h.w * s3.w;
    }
  }
  float4 b4 = *reinterpret_cast<const float4*>(&bias[oq]);
#pragma unroll
  for (int m = 0; m < 4; m++) {
    float inv = 1.0f / fmaxf((float)deg[base + ng + m], 1.0f);
    float4 o4 = {fmaxf(accA[m][0] * inv + accS[m][0] + b4.x, 0.0f),
                 fmaxf(accA[m][1] * inv + accS[m][1] + b4.y, 0.0f),
                 fmaxf(accA[m][2] * inv + accS[m][2] + b4.z, 0.0f),
                 fmaxf(accA[m][3] * inv + accS[m][3] + b4.w, 0.0f)};
    *reinterpret_cast<float4*>(&out[(size_t)(base + ng + m) * H + oq]) = o4;
  }
}

// out = e + sigm(e@WT+b)*(nf - e)   (NB=64; e staged in LDS, nf from global)
__global__ __launch_bounds__(256) void gemm_update(const float* __restrict__ Xe,
                                                   const float* __restrict__ WT,
                                                   const float* __restrict__ bias,
                                                   const float* __restrict__ nf,
                                                   float* __restrict__ out) {
  __shared__ float sX[64 * H];
  int t = threadIdx.x;
  int base = blockIdx.x * 64;
  const float4* gx = reinterpret_cast<const float4*>(Xe + (size_t)base * H);
  float4* sx4 = reinterpret_cast<float4*>(sX);
#pragma unroll
  for (int i = 0; i < 8; i++) sx4[t + 256 * i] = gx[t + 256 * i];
  __syncthreads();
  int oq = (t & 31) * 4, ng = (t >> 5) * 8;
  float acc[8][4] = {};
  for (int k = 0; k < H; k += 4) {
    float4 w0 = *reinterpret_cast<const float4*>(&WT[(k + 0) * H + oq]);
    float4 w1 = *reinterpret_cast<const float4*>(&WT[(k + 1) * H + oq]);
    float4 w2 = *reinterpret_cast<const float4*>(&WT[(k + 2) * H + oq]);
    float4 w3 = *reinterpret_cast<const float4*>(&WT[(k + 3) * H + oq]);
#pragma unroll
    for (int m = 0; m < 8; m++) {
      float4 x = *reinterpret_cast<const float4*>(&sX[(ng + m) * H + k]);
      acc[m][0] += x.x * w0.x + x.y * w1.x + x.z * w2.x + x.w * w3.x;
      acc[m][1] += x.x * w0.y + x.y * w1.y + x.z * w2.y + x.w * w3.y;
      acc[m][2] += x.x * w0.z + x.y * w1.z + x.z * w2.z + x.w * w3.z;
      acc[m][3] += x.x * w0.w + x.y * w1.w + x.z * w2.w + x.w * w3.w;
    }
  }
  float4 b4 = *reinterpret_cast<const float4*>(&bias[oq]);
#pragma unroll
  for (int m = 0; m < 8; m++) {
    size_t row = (size_t)(base + ng + m) * H;
    float4 e4 = *reinterpret_cast<const float4*>(&sX[(ng + m) * H + oq]);
    float4 f4 = *reinterpret_cast<const float4*>(&nf[row + oq]);
    float4 o4 = {e4.x + sigm(acc[m][0] + b4.x) * (f4.x - e4.x),
                 e4.y + sigm(acc[m][1] + b4.y) * (f4.y - e4.y),
                 e4.z + sigm(acc[m][2] + b4.z) * (f4.z - e4.z),
                 e4.w + sigm(acc[m][3] + b4.w) * (f4.w - e4.w)};
    *reinterpret_cast<float4*>(&out[row + oq]) = o4;
  }
}

// ===========================================================================
// CSR build (per t): deg histogram -> exclusive scan -> fill.
// ===========================================================================
__global__ __launch_bounds__(256) void edge_hist(const int* __restrict__ d, int* __restrict__ deg) {
  int e = blockIdx.x * 256 + threadIdx.x;
  if (e < E) atomicAdd(&deg[d[e]], 1);
}

__global__ __launch_bounds__(1024) void scan_deg(const int* __restrict__ deg,
                                                 int* __restrict__ rowptr,
                                                 int* __restrict__ wpos) {
  __shared__ int buf[1024];
  __shared__ int carry;
  int tid = threadIdx.x;
  if (tid == 0) carry = 0;
  __syncthreads();
  for (int base = 0; base < NE; base += 1024) {
    int idx = base + tid;
    int v = idx < NE ? deg[idx] : 0;
    buf[tid] = v;
    __syncthreads();
    for (int off = 1; off < 1024; off <<= 1) {
      int x = tid >= off ? buf[tid - off] : 0;
      __syncthreads();
      buf[tid] += x;
      __syncthreads();
    }
    int excl = carry + buf[tid] - v;
    int total = buf[1023];
    if (idx < NE) { rowptr[idx] = excl; wpos[idx] = excl; }
    __syncthreads();
    if (tid == 0) carry += total;
    __syncthreads();
  }
  if (tid == 0) rowptr[NE] = carry;
}

__global__ __launch_bounds__(256) void edge_fill(const int* __restrict__ d,
                                                 int* __restrict__ wpos,
                                                 int* __restrict__ elist) {
  int e = blockIdx.x * 256 + threadIdx.x;
  if (e >= E) return;
  int p = atomicAdd(&wpos[d[e]], 1);
  elist[p] = e;
}

// agg[n][dim] = sum_{e: d[e]==n} h[s[e]][dim] + ef[r[e]][dim]   (2 nodes/blk)
__global__ __launch_bounds__(256) void rgcn_gather(const float* __restrict__ h,
                                                   const float* __restrict__ ef,
                                                   const int* __restrict__ rowptr,
                                                   const int* __restrict__ elist,
                                                   const int* __restrict__ s,
                                                   const int* __restrict__ r,
                                                   float* __restrict__ agg) {
  int node = blockIdx.x * 2 + (threadIdx.x >> 7);
  int dim  = threadIdx.x & 127;
  int b = rowptr[node], e2 = rowptr[node + 1];
  float acc = 0.0f;
  for (int i = b; i < e2; i++) {
    int e = elist[i];
    acc += h[(size_t)s[e] * H + dim] + ef[(size_t)r[e] * H + dim];
  }
  agg[(size_t)node * H + dim] = acc;
}

// ---- _agg_rel: bitmask scatter + masked mean -------------------------------
__global__ __launch_bounds__(256) void mask_scatter(const int* __restrict__ s,
                                                    const int* __restrict__ d,
                                                    const int* __restrict__ r,
                                                    unsigned int* __restrict__ mask) {
  int e = blockIdx.x * 256 + threadIdx.x;
  if (e >= E) return;
  int ri = r[e], si = s[e], di = d[e];
  atomicOr(&mask[(size_t)ri * MW + (si >> 5)], 1u << (si & 31));
  atomicOr(&mask[(size_t)ri * MW + (di >> 5)], 1u << (di & 31));
}

__global__ __launch_bounds__(128) void agg_rel_sum(const unsigned int* __restrict__ mask,
                                                   const float* __restrict__ ent,
                                                   float* __restrict__ rsum,
                                                   float* __restrict__ rcnt) {
  int rel = blockIdx.x, part = blockIdx.y, tid = threadIdx.x;
  const int WPS = (MWU + 7) / 8;  // 157
  int w0 = part * WPS;
  int w1 = w0 + WPS < MWU ? w0 + WPS : MWU;
  float acc = 0.0f, cnt = 0.0f;
  const unsigned int* mrow = mask + (size_t)rel * MW;
  for (int w = w0; w < w1; w++) {
    unsigned int bits = mrow[w];
    if (!bits) continue;
    cnt += (float)__popc(bits);
    int base = w << 5;
    while (bits) {
      int b = __ffs(bits) - 1;
      bits &= bits - 1;
      acc += ent[(size_t)(base + b) * H + tid];
    }
  }
  atomicAdd(&rsum[rel * H + tid], acc);
  if (tid == 0) atomicAdd(&rcnt[rel], cnt);
}

// ---- relation GRU (finalize fused) + row normalize, one block/relation -----
__global__ __launch_bounds__(128) void rel_gru(const float* __restrict__ rsum,
                                               const float* __restrict__ rcnt,
                                               const float* __restrict__ rel_param,
                                               const float* __restrict__ relh,
                                               const float* __restrict__ wih,
                                               const float* __restrict__ whh,
                                               const float* __restrict__ bih,
                                               const float* __restrict__ bhh,
                                               float* __restrict__ outp) {
  int rel = blockIdx.x, tid = threadIdx.x;
  __shared__ float sx[2 * H], sh[H], red[H];
  float c = rcnt[rel];
  sx[tid]     = c > 0.0f ? rsum[rel * H + tid] / fmaxf(c, 1.0f) : 0.0f;
  sx[H + tid] = rel_param[rel * H + tid];
  sh[tid]     = relh[rel * H + tid];
  __syncthreads();
  float gr = bih[tid], gz = bih[H + tid], gn = bih[2 * H + tid];
  for (int k = 0; k < 2 * H; k++) {
    float x = sx[k];
    gr += x * wih[(size_t)tid * 2 * H + k];
    gz += x * wih[(size_t)(H + tid) * 2 * H + k];
    gn += x * wih[(size_t)(2 * H + tid) * 2 * H + k];
  }
  float hr = bhh[tid], hz = bhh[H + tid], hn = bhh[2 * H + tid];
  for (int k = 0; k < H; k++) {
    float hv = sh[k];
    hr += hv * whh[tid * H + k];
    hz += hv * whh[(H + tid) * H + k];
    hn += hv * whh[(2 * H + tid) * H + k];
  }
  float r = sigm(gr + hr), z = sigm(gz + hz), nn = tanhf(gn + r * hn);
  float val = (1.0f - z) * nn + z * sh[tid];
  red[tid] = val * val;
  __syncthreads();
  for (int s2 = 64; s2 > 0; s2 >>= 1) {
    if (tid < s2) red[tid] += red[tid + s2];
    __syncthreads();
  }
  float inv = 1.0f / fmaxf(sqrtf(red[0]), 1e-12f);
  outp[rel * H + tid] = val * inv;
}

// ---- ConvTransE front ------------------------------------------------------
__global__ __launch_bounds__(256) void conv_front(const float* __restrict__ fa,
                                                  const int* __restrict__ ia,
                                                  const float* __restrict__ fbm,
                                                  const int* __restrict__ ib,
                                                  const float* __restrict__ ck,
                                                  const float* __restrict__ ckb,
                                                  const float* __restrict__ fw,
                                                  const float* __restrict__ fbias,
                                                  float* __restrict__ Z) {
  __shared__ float sy[4 * C * H];  // 64KB
  int q0 = blockIdx.x * 4;
  int tid = threadIdx.x;
  for (int i = tid; i < 4 * C * H; i += 256) {
    int q = i >> 12, c = (i >> 7) & 31, p = i & 127;
    const float* xa = fa + (size_t)ia[q0 + q] * H;
    const float* xb = fbm + (size_t)ib[q0 + q] * H;
    float acc = ckb[c];
#pragma unroll
    for (int kk2 = 0; kk2 < 3; kk2++) {
      int pos = p + kk2 - 1;
      if (pos >= 0 && pos < H)
        acc += xa[pos] * ck[c * 6 + kk2] + xb[pos] * ck[c * 6 + 3 + kk2];
    }
    sy[i] = fmaxf(acc, 0.0f);
  }
  __syncthreads();
  int o = tid & 127, g = tid >> 7;
  float acc0 = fbias[o], acc1 = fbias[o];
  const float* wrow = fw + (size_t)o * (C * H);
  const float* y0 = &sy[(g * 2 + 0) * C * H];
  const float* y1 = &sy[(g * 2 + 1) * C * H];
  for (int j = 0; j < C * H; j += 4) {
    float4 w = *reinterpret_cast<const float4*>(&wrow[j]);
    float4 a = *reinterpret_cast<const float4*>(&y0[j]);
    float4 b = *reinterpret_cast<const float4*>(&y1[j]);
    acc0 += a.x * w.x + a.y * w.y + a.z * w.z + a.w * w.w;
    acc1 += b.x * w.x + b.y * w.y + b.z * w.z + b.w * w.w;
  }
  Z[(size_t)(q0 + g * 2 + 0) * H + o] = fmaxf(acc0, 0.0f);
  Z[(size_t)(q0 + g * 2 + 1) * H + o] = fmaxf(acc1, 0.0f);
}

// ---- logits: out[q][m] = Z[q,:]·F[m,:]; 128x128 tile, Kc=32, 8x8/thread ----
__global__ __launch_bounds__(256) void logits_gemm2(const float* __restrict__ Z,
                                                    const float* __restrict__ F,
                                                    float* __restrict__ out,
                                                    int M) {
  __shared__ float sZ[32 * H];  // [k][q] 16KB
  __shared__ float sF[32 * H];  // [k][m] 16KB
  int t = threadIdx.x;
  int bq = blockIdx.y * 128, bm = blockIdx.x * 128;
  int tx = t & 15, ty = t >> 4;
  float acc[8][8] = {};
  int qld = t & 127, kh = (t >> 7) * 16;
  int mld = bm + qld;
  if (mld >= M) mld = M - 1;
  for (int kc = 0; kc < H; kc += 32) {
    __syncthreads();
    const float* zr = Z + (size_t)(bq + qld) * H + kc + kh;
    const float* fr = F + (size_t)mld * H + kc + kh;
#pragma unroll
    for (int j = 0; j < 16; j += 4) {
      float4 v = *reinterpret_cast<const float4*>(zr + j);
      sZ[(kh + j + 0) * H + qld] = v.x;
      sZ[(kh + j + 1) * H + qld] = v.y;
      sZ[(kh + j + 2) * H + qld] = v.z;
      sZ[(kh + j + 3) * H + qld] = v.w;
      float4 f = *reinterpret_cast<const float4*>(fr + j);
      sF[(kh + j + 0) * H + qld] = f.x;
      sF[(kh + j + 1) * H + qld] = f.y;
      sF[(kh + j + 2) * H + qld] = f.z;
      sF[(kh + j + 3) * H + qld] = f.w;
    }
    __syncthreads();
    for (int k = 0; k < 32; k++) {
      float4 za = *reinterpret_cast<const float4*>(&sZ[k * H + ty * 8]);
      float4 zb = *reinterpret_cast<const float4*>(&sZ[k * H + ty * 8 + 4]);
      float4 fa = *reinterpret_cast<const float4*>(&sF[k * H + tx * 8]);
      float4 fb = *reinterpret_cast<const float4*>(&sF[k * H + tx * 8 + 4]);
      float zq[8] = {za.x, za.y, za.z, za.w, zb.x, zb.y, zb.z, zb.w};
      float fm[8] = {fa.x, fa.y, fa.z, fa.w, fb.x, fb.y, fb.z, fb.w};
#pragma unroll
      for (int i = 0; i < 8; i++)
#pragma unroll
        for (int j = 0; j < 8; j++) acc[i][j] += zq[i] * fm[j];
    }
  }
  int m0 = bm + tx * 8;
  if (m0 >= M) return;
#pragma unroll
  for (int i = 0; i < 8; i++) {
    size_t row = (size_t)(bq + ty * 8 + i) * (size_t)M + m0;
    float4 o1 = {acc[i][0], acc[i][1], acc[i][2], acc[i][3]};
    float4 o2 = {acc[i][4], acc[i][5], acc[i][6], acc[i][7]};
    *reinterpret_cast<float4*>(&out[row]) = o1;
    *reinterpret_cast<float4*>(&out[row + 4]) = o2;
  }
}

}  // namespace

extern "C" void kernel_launch(void* const* d_in, const int* in_sizes, int n_in,
                              void* d_out, int out_size, void* d_ws, size_t ws_size,
                              hipStream_t stream) {
  (void)in_sizes; (void)n_in; (void)out_size; (void)ws_size;
  const float* ent_embeds = (const float*)d_in[0];
  const float* rel_embeds = (const float*)d_in[1];
  const float* mmt_embed  = (const float*)d_in[2];
  const float* tc_w  = (const float*)d_in[3];
  const float* tc_b  = (const float*)d_in[4];
  const float* tc_pw = (const float*)d_in[5];
  const float* tc_pb = (const float*)d_in[6];
  const float* g1_wih = (const float*)d_in[7];
  const float* g1_whh = (const float*)d_in[8];
  const float* g1_bih = (const float*)d_in[9];
  const float* g1_bhh = (const float*)d_in[10];
  const float* l1_wih = (const float*)d_in[11];
  const float* l1_bih = (const float*)d_in[13];
  const float* l1_bhh = (const float*)d_in[14];
  const float* l2_wih = (const float*)d_in[15];
  const float* l2_bih = (const float*)d_in[17];
  const float* l2_bhh = (const float*)d_in[18];
  const float* lin_w = (const float*)d_in[19];
  const float* lin_b = (const float*)d_in[20];
  const float* rgcn_wn = (const float*)d_in[21];
  const float* rgcn_ws = (const float*)d_in[22];
  const float* rgcn_b  = (const float*)d_in[23];
  const float* oc_k  = (const float*)d_in[24];
  const float* oc_kb = (const float*)d_in[25];
  const float* oc_fw = (const float*)d_in[26];
  const float* oc_fb = (const float*)d_in[27];
  const float* rc_k  = (const float*)d_in[28];
  const float* rc_kb = (const float*)d_in[29];
  const float* rc_fw = (const float*)d_in[30];
  const float* rc_fb = (const float*)d_in[31];
  const int* src  = (const int*)d_in[32];
  const int* dst  = (const int*)d_in[33];
  const int* rid  = (const int*)d_in[34];
  const int* qsub = (const int*)d_in[35];
  const int* qrel = (const int*)d_in[36];
  const int* qobj = (const int*)d_in[37];

  float* out = (float*)d_out;
  float* ws  = (float*)d_ws;

  // ---- d_ws layout (floats), ~23.2 MB ----
  size_t off = 0;
  float* entF = ws + off; off += NEH;                 // final ent (read by logits)
  float* relhB[3] = {ws + off, ws + off + (size_t)NR * H, ws + off + 2 * (size_t)NR * H};
  off += 3 * (size_t)NR * H;
  float* rel_sum = ws + off; off += (size_t)NR * H;   // rel_sum + rcnt adjacent
  float* rcnt    = ws + off; off += NR;
  float* mmtbuf0 = ws + off; off += H;
  float* mmtbuf1 = ws + off; off += H;
  float* vbuf    = ws + off; off += H;
  float* MT      = ws + off; off += (size_t)H * H;
  float* WTlin   = ws + off; off += (size_t)H * H;
  float* Zo      = ws + off; off += (size_t)NT * H;
  float* Zr      = ws + off; off += (size_t)NT * H;
  unsigned int* mask = (unsigned int*)(ws + off); off += (size_t)NR * MW;

  // ---- d_out as scratch: 4 rotating NE*H buffers + CSR ints in the tail ----
  float* B[4] = {out, out + NEH, out + 2 * NEH, out + 3 * NEH};
  int* itail   = (int*)(out + 4 * NEH);               // ~20.7M int slots free
  int* deg     = itail;                                // NE
  int* rowptr  = itail + NE;                           // NE+1
  int* wpos    = itail + 2 * NE + 1;                   // NE
  int* elist   = itail + 3 * NE + 1;                   // E
  float* mmtb[2] = {mmtbuf0, mmtbuf1};

  // init
  norm_rows<<<(NE + 3) / 4, 256, 0, stream>>>(ent_embeds, B[0], NE);
  norm_rows<<<(NR + 3) / 4, 256, 0, stream>>>(rel_embeds, relhB[0], NR);
  copy_vec<<<1, 128, 0, stream>>>(mmt_embed, mmtbuf0, H);
  transpose128<<<64, 256, 0, stream>>>(lin_w, WTlin);

  int cur = 0, curRelh = 0;
  for (int t = 0; t < T; t++) {
    int fr[3], fi = 0;
    for (int b = 0; b < 4; b++) if (b != cur) fr[fi++] = b;
    int bX = fr[0], bG = fr[1], bY = fr[2];
    const int* s_t = src + (size_t)t * E;
    const int* d_t = dst + (size_t)t * E;
    const int* r_t = rid + (size_t)t * E;

    // mmt GRU pair + v; tconv map M
    mmt_step<<<1, 128, 0, stream>>>(mmtb[t & 1], l1_wih, l1_bih, l1_bhh,
                                    l2_wih, l2_bih, l2_bhh, tc_w, tc_b,
                                    mmtb[(t + 1) & 1], vbuf);
    build_M<<<H, H, 0, stream>>>(vbuf, tc_pw, MT);
    gemm_bias<<<NE / 64, 256, 0, stream>>>(B[cur], MT, tc_pb, B[bX]);          // ent_t
    gemm_bias<<<NR / 64, 256, 0, stream>>>(relhB[curRelh], MT, tc_pb, relhB[2]);

    // _agg_rel on ent_t (bitmask) + relation GRU
    hipMemsetAsync(mask, 0, (size_t)NR * MW * 4, stream);
    mask_scatter<<<(E + 255) / 256, 256, 0, stream>>>(s_t, d_t, r_t, mask);
    hipMemsetAsync(rel_sum, 0, ((size_t)NR * H + NR) * 4, stream);
    agg_rel_sum<<<dim3(NR, 8), 128, 0, stream>>>(mask, B[bX], rel_sum, rcnt);
    int nextRelh = 1 - curRelh;
    rel_gru<<<NR, 128, 0, stream>>>(rel_sum, rcnt, rel_embeds, relhB[2],
                                    g1_wih, g1_whh, g1_bih, g1_bhh, relhB[nextRelh]);

    // CSR build (once per t, reused by both layers)
    hipMemsetAsync(deg, 0, (size_t)NE * 4, stream);
    edge_hist<<<(E + 255) / 256, 256, 0, stream>>>(d_t, deg);
    scan_deg<<<1, 1024, 0, stream>>>(deg, rowptr, wpos);
    edge_fill<<<(E + 255) / 256, 256, 0, stream>>>(d_t, wpos, elist);

    // RGCN layer 0
    rgcn_gather<<<NE / 2, 256, 0, stream>>>(B[bX], relhB[nextRelh], rowptr, elist, s_t, r_t, B[bG]);
    gemm_rgcn<<<NE / 32, 256, 0, stream>>>(B[bG], B[bX], rgcn_wn, rgcn_ws, rgcn_b, deg, B[bY]);
    // RGCN layer 1
    rgcn_gather<<<NE / 2, 256, 0, stream>>>(B[bY], relhB[nextRelh], rowptr, elist, s_t, r_t, B[bG]);
    gemm_rgcn<<<NE / 32, 256, 0, stream>>>(B[bG], B[bY], rgcn_wn + H * H, rgcn_ws + H * H,
                                           rgcn_b + H, deg, B[cur]);

    // nf = norm(h2); ent_{t+1} = ent_t + sigm(ent_t W^T + b)*(nf - ent_t)
    norm_rows<<<NE / 4, 256, 0, stream>>>(B[cur], B[cur], NE);
    float* entDst = (t == T - 1) ? entF : B[bY];
    gemm_update<<<NE / 64, 256, 0, stream>>>(B[bX], WTlin, lin_b, B[cur], entDst);

    cur = bY;
    curRelh = nextRelh;
  }

  float* relhF = relhB[curRelh];

  // ConvTransE fronts
  conv_front<<<NT / 4, 256, 0, stream>>>(entF, qsub, relhF, qrel, oc_k, oc_kb, oc_fw, oc_fb, Zo);
  conv_front<<<NT / 4, 256, 0, stream>>>(entF, qsub, entF, qobj, rc_k, rc_kb, rc_fw, rc_fb, Zr);

  // logits (reads only d_ws; writes d_out)
  logits_gemm2<<<dim3((NE + 127) / 128, NT / 128), 256, 0, stream>>>(Zo, entF, out, NE);
  logits_gemm2<<<dim3(NR / 128, NT / 128), 256, 0, stream>>>(Zr, relhF, out + (size_t)NT * NE, NR);
}

// Round 3
// 2305.142 us; speedup vs baseline: 1.7364x; 1.0961x over previous
//
#include <hip/hip_runtime.h>
#include <cmath>

// ---------------------------------------------------------------------------
// Tconv_35450660061268 — R3.
//   * conv_front rewritten as split-K GEMM (8q x K/4 per block, 4-acc ILP,
//     wave-uniform y broadcast) + Zpart finalize. Was 1-wave/SIMD latency-bound.
//   * norm fused into gemm_rgcn layer-2 epilogue (shfl_xor row reduce).
//   * scan_deg via wave shfl scan (2 barriers/chunk vs 10).
//   * mask_scatter+edge_hist merged; mmt_step/rel_gru float4 weight reads.
//   * agg_rel_sum 32 partitions (shorter serial dependent-load chains).
// ---------------------------------------------------------------------------

namespace {

constexpr int H   = 128;
constexpr int KK  = 4;
constexpr int C   = 32;
constexpr int NE  = 40000;
constexpr int NR  = 256;
constexpr int T   = 4;
constexpr int E   = 100000;
constexpr int NT  = 1024;
constexpr int PIN = 388;     // H*KK - H + KK
constexpr int MW  = 1280;    // mask words per relation (padded; 1250 used)
constexpr int MWU = 1250;
constexpr size_t NEH = (size_t)NE * H;

__device__ __forceinline__ float sigm(float x) { return 1.0f / (1.0f + expf(-x)); }

// ---- row L2-normalize, one wave per row (init only) ------------------------
__global__ __launch_bounds__(256) void norm_rows(const float* __restrict__ in,
                                                 float* __restrict__ out, int n) {
  int row  = blockIdx.x * 4 + (threadIdx.x >> 6);
  int lane = threadIdx.x & 63;
  if (row >= n) return;
  const float2* ip = reinterpret_cast<const float2*>(in + (size_t)row * H);
  float2 v = ip[lane];
  float ss = v.x * v.x + v.y * v.y;
#pragma unroll
  for (int off = 32; off; off >>= 1) ss += __shfl_xor(ss, off);
  float inv = 1.0f / fmaxf(sqrtf(ss), 1e-12f);
  float2 o; o.x = v.x * inv; o.y = v.y * inv;
  reinterpret_cast<float2*>(out + (size_t)row * H)[lane] = o;
}

__global__ void copy_vec(const float* __restrict__ a, float* __restrict__ b, int n) {
  int i = blockIdx.x * blockDim.x + threadIdx.x;
  if (i < n) b[i] = a[i];
}

__global__ __launch_bounds__(256) void transpose128(const float* __restrict__ in,
                                                    float* __restrict__ out) {
  int i = blockIdx.x * 256 + threadIdx.x;   // grid 64
  int o = i >> 7, k = i & 127;
  out[k * H + o] = in[o * H + k];
}

// ---- mmt GRU pair + gated update + v = mmt_new @ tc_w^T + tc_b (1 block) ---
__global__ __launch_bounds__(128) void mmt_step(
    const float* __restrict__ mmt_in,
    const float* __restrict__ w1, const float* __restrict__ bi1, const float* __restrict__ bh1,
    const float* __restrict__ w2, const float* __restrict__ bi2, const float* __restrict__ bh2,
    const float* __restrict__ tcw, const float* __restrict__ tcb,
    float* __restrict__ mmt_out, float* __restrict__ vout) {
  __shared__ float sm[H], sm2[H];
  int t = threadIdx.x;
  sm[t] = mmt_in[t];
  __syncthreads();
  float g1r = bi1[t], g1z = bi1[H + t], g1n = bi1[2 * H + t];
  float g2r = bi2[t], g2z = bi2[H + t], g2n = bi2[2 * H + t];
  {
    const float4* r1p = reinterpret_cast<const float4*>(w1 + (size_t)t * H);
    const float4* z1p = reinterpret_cast<const float4*>(w1 + (size_t)(H + t) * H);
    const float4* n1p = reinterpret_cast<const float4*>(w1 + (size_t)(2 * H + t) * H);
    const float4* r2p = reinterpret_cast<const float4*>(w2 + (size_t)t * H);
    const float4* z2p = reinterpret_cast<const float4*>(w2 + (size_t)(H + t) * H);
    const float4* n2p = reinterpret_cast<const float4*>(w2 + (size_t)(2 * H + t) * H);
    const float4* x4 = reinterpret_cast<const float4*>(sm);
    for (int k = 0; k < 32; k++) {
      float4 x = x4[k];
      float4 a = r1p[k], b = z1p[k], c = n1p[k], d = r2p[k], e = z2p[k], f = n2p[k];
      g1r += x.x * a.x + x.y * a.y + x.z * a.z + x.w * a.w;
      g1z += x.x * b.x + x.y * b.y + x.z * b.z + x.w * b.w;
      g1n += x.x * c.x + x.y * c.y + x.z * c.z + x.w * c.w;
      g2r += x.x * d.x + x.y * d.y + x.z * d.z + x.w * d.w;
      g2z += x.x * e.x + x.y * e.y + x.z * e.z + x.w * e.w;
      g2n += x.x * f.x + x.y * f.y + x.z * f.z + x.w * f.w;
    }
  }
  float r1 = sigm(g1r + bh1[t]), z1 = sigm(g1z + bh1[H + t]);
  float n1 = tanhf(g1n + r1 * bh1[2 * H + t]);
  float nmmt = (1.0f - z1) * n1;
  float r2 = sigm(g2r + bh2[t]), z2 = sigm(g2z + bh2[H + t]);
  float n2 = tanhf(g2n + r2 * bh2[2 * H + t]);
  float gg = (1.0f - z2) * n2;
  float m  = sm[t];
  float mo = m + gg * (nmmt - m);
  mmt_out[t] = mo;
  sm2[t] = mo;
  __syncthreads();
  float v = tcb[t];
  {
    const float4* wp = reinterpret_cast<const float4*>(tcw + (size_t)t * H);
    const float4* x4 = reinterpret_cast<const float4*>(sm2);
    for (int k = 0; k < 32; k++) {
      float4 x = x4[k], w = wp[k];
      v += x.x * w.x + x.y * w.y + x.z * w.z + x.w * w.w;
    }
  }
  vout[t] = v;
}

// ---- build MT[p*H+o] = M[o][p] (k-major tconv map) -------------------------
__global__ __launch_bounds__(128) void build_M(const float* __restrict__ v,
                                               const float* __restrict__ pw,
                                               float* __restrict__ MT) {
  int o = blockIdx.x, p = threadIdx.x;
  __shared__ float sp[PIN];
  __shared__ float sv[H];
  for (int i = p; i < PIN; i += H) sp[i] = pw[(size_t)o * PIN + i];
  sv[p] = v[p];
  __syncthreads();
  float acc = 0.0f;
  int jlo = p - 31 > 0 ? p - 31 : 0;
  int jhi = p < 96 ? p : 96;
#pragma unroll
  for (int k = 0; k < KK; k++)
    for (int j = jlo; j <= jhi; j++) acc += sp[k * 97 + j] * sv[k * 32 + (p - j)];
  MT[p * H + o] = acc;
}

// ===========================================================================
// Register-tiled GEMM family (unchanged core from R2).
// ===========================================================================
__global__ __launch_bounds__(256) void gemm_bias(const float* __restrict__ X,
                                                 const float* __restrict__ WT,
                                                 const float* __restrict__ bias,
                                                 float* __restrict__ out) {
  __shared__ float sX[64 * H];
  int t = threadIdx.x;
  int base = blockIdx.x * 64;
  const float4* gx = reinterpret_cast<const float4*>(X + (size_t)base * H);
  float4* sx4 = reinterpret_cast<float4*>(sX);
#pragma unroll
  for (int i = 0; i < 8; i++) sx4[t + 256 * i] = gx[t + 256 * i];
  __syncthreads();
  int oq = (t & 31) * 4, ng = (t >> 5) * 8;
  float acc[8][4] = {};
  for (int k = 0; k < H; k += 4) {
    float4 w0 = *reinterpret_cast<const float4*>(&WT[(k + 0) * H + oq]);
    float4 w1 = *reinterpret_cast<const float4*>(&WT[(k + 1) * H + oq]);
    float4 w2 = *reinterpret_cast<const float4*>(&WT[(k + 2) * H + oq]);
    float4 w3 = *reinterpret_cast<const float4*>(&WT[(k + 3) * H + oq]);
#pragma unroll
    for (int m = 0; m < 8; m++) {
      float4 x = *reinterpret_cast<const float4*>(&sX[(ng + m) * H + k]);
      acc[m][0] += x.x * w0.x + x.y * w1.x + x.z * w2.x + x.w * w3.x;
      acc[m][1] += x.x * w0.y + x.y * w1.y + x.z * w2.y + x.w * w3.y;
      acc[m][2] += x.x * w0.z + x.y * w1.z + x.z * w2.z + x.w * w3.z;
      acc[m][3] += x.x * w0.w + x.y * w1.w + x.z * w2.w + x.w * w3.w;
    }
  }
  float4 b4 = *reinterpret_cast<const float4*>(&bias[oq]);
#pragma unroll
  for (int m = 0; m < 8; m++) {
    float4 o4 = {acc[m][0] + b4.x, acc[m][1] + b4.y, acc[m][2] + b4.z, acc[m][3] + b4.w};
    *reinterpret_cast<float4*>(&out[(size_t)(base + ng + m) * H + oq]) = o4;
  }
}

// RGCN layer fused: out = relu((A@wn)*inv_deg + Hm@ws + b); optional row-norm.
__global__ __launch_bounds__(256) void gemm_rgcn(const float* __restrict__ A,
                                                 const float* __restrict__ Hm,
                                                 const float* __restrict__ wn,
                                                 const float* __restrict__ ws,
                                                 const float* __restrict__ bias,
                                                 const int* __restrict__ deg,
                                                 float* __restrict__ out,
                                                 int donorm) {
  __shared__ float sA[32 * H];
  __shared__ float sH[32 * H];
  int t = threadIdx.x;
  int base = blockIdx.x * 32;
  const float4* ga = reinterpret_cast<const float4*>(A + (size_t)base * H);
  const float4* gh = reinterpret_cast<const float4*>(Hm + (size_t)base * H);
  float4* sa4 = reinterpret_cast<float4*>(sA);
  float4* sh4 = reinterpret_cast<float4*>(sH);
#pragma unroll
  for (int i = 0; i < 4; i++) { sa4[t + 256 * i] = ga[t + 256 * i]; sh4[t + 256 * i] = gh[t + 256 * i]; }
  __syncthreads();
  int oq = (t & 31) * 4, ng = (t >> 5) * 4;
  float accA[4][4] = {}, accS[4][4] = {};
  for (int k = 0; k < H; k += 4) {
    float4 n0 = *reinterpret_cast<const float4*>(&wn[(k + 0) * H + oq]);
    float4 n1 = *reinterpret_cast<const float4*>(&wn[(k + 1) * H + oq]);
    float4 n2 = *reinterpret_cast<const float4*>(&wn[(k + 2) * H + oq]);
    float4 n3 = *reinterpret_cast<const float4*>(&wn[(k + 3) * H + oq]);
    float4 s0 = *reinterpret_cast<const float4*>(&ws[(k + 0) * H + oq]);
    float4 s1 = *reinterpret_cast<const float4*>(&ws[(k + 1) * H + oq]);
    float4 s2 = *reinterpret_cast<const float4*>(&ws[(k + 2) * H + oq]);
    float4 s3 = *reinterpret_cast<const float4*>(&ws[(k + 3) * H + oq]);
#pragma unroll
    for (int m = 0; m < 4; m++) {
      float4 a = *reinterpret_cast<const float4*>(&sA[(ng + m) * H + k]);
      float4 h = *reinterpret_cast<const float4*>(&sH[(ng + m) * H + k]);
      accA[m][0] += a.x * n0.x + a.y * n1.x + a.z * n2.x + a.w * n3.x;
      accA[m][1] += a.x * n0.y + a.y * n1.y + a.z * n2.y + a.w * n3.y;
      accA[m][2] += a.x * n0.z + a.y * n1.z + a.z * n2.z + a.w * n3.z;
      accA[m][3] += a.x * n0.w + a.y * n1.w + a.z * n2.w + a.w * n3.w;
      accS[m][0] += h.x * s0.x + h.y * s1.x + h.z * s2.x + h.w * s3.x;
      accS[m][1] += h.x * s0.y + h.y * s1.y + h.z * s2.y + h.w * s3.y;
      accS[m][2] += h.x * s0.z + h.y * s1.z + h.z * s2.z + h.w * s3.z;
      accS[m][3] += h.x * s0.w + h.y * s1.w + h.z * s2.w + h.w * s3.w;
    }
  }
  float4 b4 = *reinterpret_cast<const float4*>(&bias[oq]);
  float v[4][4];
#pragma unroll
  for (int m = 0; m < 4; m++) {
    float inv = 1.0f / fmaxf((float)deg[base + ng + m], 1.0f);
    v[m][0] = fmaxf(accA[m][0] * inv + accS[m][0] + b4.x, 0.0f);
    v[m][1] = fmaxf(accA[m][1] * inv + accS[m][1] + b4.y, 0.0f);
    v[m][2] = fmaxf(accA[m][2] * inv + accS[m][2] + b4.z, 0.0f);
    v[m][3] = fmaxf(accA[m][3] * inv + accS[m][3] + b4.w, 0.0f);
  }
  if (donorm) {
    // row m lives across the 32 lanes sharing this half-wave (oq covers 128)
#pragma unroll
    for (int m = 0; m < 4; m++) {
      float ss = v[m][0]*v[m][0] + v[m][1]*v[m][1] + v[m][2]*v[m][2] + v[m][3]*v[m][3];
#pragma unroll
      for (int off = 16; off; off >>= 1) ss += __shfl_xor(ss, off);
      float inv = 1.0f / fmaxf(sqrtf(ss), 1e-12f);
      v[m][0] *= inv; v[m][1] *= inv; v[m][2] *= inv; v[m][3] *= inv;
    }
  }
#pragma unroll
  for (int m = 0; m < 4; m++) {
    float4 o4 = {v[m][0], v[m][1], v[m][2], v[m][3]};
    *reinterpret_cast<float4*>(&out[(size_t)(base + ng + m) * H + oq]) = o4;
  }
}

// out = e + sigm(e@WT+b)*(nf - e)
__global__ __launch_bounds__(256) void gemm_update(const float* __restrict__ Xe,
                                                   const float* __restrict__ WT,
                                                   const float* __restrict__ bias,
                                                   const float* __restrict__ nf,
                                                   float* __restrict__ out) {
  __shared__ float sX[64 * H];
  int t = threadIdx.x;
  int base = blockIdx.x * 64;
  const float4* gx = reinterpret_cast<const float4*>(Xe + (size_t)base * H);
  float4* sx4 = reinterpret_cast<float4*>(sX);
#pragma unroll
  for (int i = 0; i < 8; i++) sx4[t + 256 * i] = gx[t + 256 * i];
  __syncthreads();
  int oq = (t & 31) * 4, ng = (t >> 5) * 8;
  float acc[8][4] = {};
  for (int k = 0; k < H; k += 4) {
    float4 w0 = *reinterpret_cast<const float4*>(&WT[(k + 0) * H + oq]);
    float4 w1 = *reinterpret_cast<const float4*>(&WT[(k + 1) * H + oq]);
    float4 w2 = *reinterpret_cast<const float4*>(&WT[(k + 2) * H + oq]);
    float4 w3 = *reinterpret_cast<const float4*>(&WT[(k + 3) * H + oq]);
#pragma unroll
    for (int m = 0; m < 8; m++) {
      float4 x = *reinterpret_cast<const float4*>(&sX[(ng + m) * H + k]);
      acc[m][0] += x.x * w0.x + x.y * w1.x + x.z * w2.x + x.w * w3.x;
      acc[m][1] += x.x * w0.y + x.y * w1.y + x.z * w2.y + x.w * w3.y;
      acc[m][2] += x.x * w0.z + x.y * w1.z + x.z * w2.z + x.w * w3.z;
      acc[m][3] += x.x * w0.w + x.y * w1.w + x.z * w2.w + x.w * w3.w;
    }
  }
  float4 b4 = *reinterpret_cast<const float4*>(&bias[oq]);
#pragma unroll
  for (int m = 0; m < 8; m++) {
    size_t row = (size_t)(base + ng + m) * H;
    float4 e4 = *reinterpret_cast<const float4*>(&sX[(ng + m) * H + oq]);
    float4 f4 = *reinterpret_cast<const float4*>(&nf[row + oq]);
    float4 o4 = {e4.x + sigm(acc[m][0] + b4.x) * (f4.x - e4.x),
                 e4.y + sigm(acc[m][1] + b4.y) * (f4.y - e4.y),
                 e4.z + sigm(acc[m][2] + b4.z) * (f4.z - e4.z),
                 e4.w + sigm(acc[m][3] + b4.w) * (f4.w - e4.w)};
    *reinterpret_cast<float4*>(&out[row + oq]) = o4;
  }
}

// ===========================================================================
// Edge prep: rel-bitmask scatter + dst-degree histogram in one pass over E.
// ===========================================================================
__global__ __launch_bounds__(256) void edge_prep(const int* __restrict__ s,
                                                 const int* __restrict__ d,
                                                 const int* __restrict__ r,
                                                 unsigned int* __restrict__ mask,
                                                 int* __restrict__ deg) {
  int e = blockIdx.x * 256 + threadIdx.x;
  if (e >= E) return;
  int ri = r[e], si = s[e], di = d[e];
  atomicOr(&mask[(size_t)ri * MW + (si >> 5)], 1u << (si & 31));
  atomicOr(&mask[(size_t)ri * MW + (di >> 5)], 1u << (di & 31));
  atomicAdd(&deg[di], 1);
}

// wave-shfl scan over deg -> rowptr (exclusive) + wpos copy
__global__ __launch_bounds__(1024) void scan_deg(const int* __restrict__ deg,
                                                 int* __restrict__ rowptr,
                                                 int* __restrict__ wpos) {
  __shared__ int wsum[16];
  __shared__ int carry_s;
  int tid = threadIdx.x, lane = tid & 63, w = tid >> 6;
  if (tid == 0) carry_s = 0;
  __syncthreads();
  for (int base = 0; base < NE; base += 1024) {
    int idx = base + tid;
    int v = idx < NE ? deg[idx] : 0;
    int x = v;
#pragma unroll
    for (int off = 1; off < 64; off <<= 1) {
      int y = __shfl_up(x, off, 64);
      if (lane >= off) x += y;
    }
    if (lane == 63) wsum[w] = x;
    __syncthreads();
    int carry = carry_s;
    int wpre = 0;
    for (int i = 0; i < w; i++) wpre += wsum[i];
    int excl = carry + wpre + x - v;
    if (idx < NE) { rowptr[idx] = excl; wpos[idx] = excl; }
    __syncthreads();
    if (tid == 1023) carry_s = carry + wpre + x;
  }
  __syncthreads();
  if (tid == 0) rowptr[NE] = carry_s;
}

__global__ __launch_bounds__(256) void edge_fill(const int* __restrict__ d,
                                                 int* __restrict__ wpos,
                                                 int* __restrict__ elist) {
  int e = blockIdx.x * 256 + threadIdx.x;
  if (e >= E) return;
  int p = atomicAdd(&wpos[d[e]], 1);
  elist[p] = e;
}

// agg[n][dim] = sum_{e: d[e]==n} h[s[e]][dim] + ef[r[e]][dim]   (2 nodes/blk)
__global__ __launch_bounds__(256) void rgcn_gather(const float* __restrict__ h,
                                                   const float* __restrict__ ef,
                                                   const int* __restrict__ rowptr,
                                                   const int* __restrict__ elist,
                                                   const int* __restrict__ s,
                                                   const int* __restrict__ r,
                                                   float* __restrict__ agg) {
  int node = blockIdx.x * 2 + (threadIdx.x >> 7);
  int dim  = threadIdx.x & 127;
  int b = rowptr[node], e2 = rowptr[node + 1];
  float acc = 0.0f;
  for (int i = b; i < e2; i++) {
    int e = elist[i];
    acc += h[(size_t)s[e] * H + dim] + ef[(size_t)r[e] * H + dim];
  }
  agg[(size_t)node * H + dim] = acc;
}

// ---- _agg_rel masked sum: 32 partitions per relation -----------------------
__global__ __launch_bounds__(128) void agg_rel_sum(const unsigned int* __restrict__ mask,
                                                   const float* __restrict__ ent,
                                                   float* __restrict__ rsum,
                                                   float* __restrict__ rcnt) {
  int rel = blockIdx.x, part = blockIdx.y, tid = threadIdx.x;
  const int WPS = (MWU + 31) / 32;  // 40
  int w0 = part * WPS;
  int w1 = w0 + WPS < MWU ? w0 + WPS : MWU;
  float acc = 0.0f, cnt = 0.0f;
  const unsigned int* mrow = mask + (size_t)rel * MW;
  for (int w = w0; w < w1; w++) {
    unsigned int bits = mrow[w];
    if (!bits) continue;
    cnt += (float)__popc(bits);
    int base = w << 5;
    while (bits) {
      int b = __ffs(bits) - 1;
      bits &= bits - 1;
      acc += ent[(size_t)(base + b) * H + tid];
    }
  }
  if (acc != 0.0f) atomicAdd(&rsum[rel * H + tid], acc);
  if (tid == 0 && cnt != 0.0f) atomicAdd(&rcnt[rel], cnt);
}

// ---- relation GRU (finalize fused) + row normalize -------------------------
__global__ __launch_bounds__(128) void rel_gru(const float* __restrict__ rsum,
                                               const float* __restrict__ rcnt,
                                               const float* __restrict__ rel_param,
                                               const float* __restrict__ relh,
                                               const float* __restrict__ wih,
                                               const float* __restrict__ whh,
                                               const float* __restrict__ bih,
                                               const float* __restrict__ bhh,
                                               float* __restrict__ outp) {
  int rel = blockIdx.x, tid = threadIdx.x;
  __shared__ float sx[2 * H], sh[H], red[H];
  float c = rcnt[rel];
  sx[tid]     = c > 0.0f ? rsum[rel * H + tid] / fmaxf(c, 1.0f) : 0.0f;
  sx[H + tid] = rel_param[rel * H + tid];
  sh[tid]     = relh[rel * H + tid];
  __syncthreads();
  float gr = bih[tid], gz = bih[H + tid], gn = bih[2 * H + tid];
  {
    const float4* rp = reinterpret_cast<const float4*>(wih + (size_t)tid * 2 * H);
    const float4* zp = reinterpret_cast<const float4*>(wih + (size_t)(H + tid) * 2 * H);
    const float4* np = reinterpret_cast<const float4*>(wih + (size_t)(2 * H + tid) * 2 * H);
    const float4* x4 = reinterpret_cast<const float4*>(sx);
    for (int k = 0; k < 64; k++) {
      float4 x = x4[k];
      float4 a = rp[k], b = zp[k], cc = np[k];
      gr += x.x * a.x + x.y * a.y + x.z * a.z + x.w * a.w;
      gz += x.x * b.x + x.y * b.y + x.z * b.z + x.w * b.w;
      gn += x.x * cc.x + x.y * cc.y + x.z * cc.z + x.w * cc.w;
    }
  }
  float hr = bhh[tid], hz = bhh[H + tid], hn = bhh[2 * H + tid];
  {
    const float4* rp = reinterpret_cast<const float4*>(whh + (size_t)tid * H);
    const float4* zp = reinterpret_cast<const float4*>(whh + (size_t)(H + tid) * H);
    const float4* np = reinterpret_cast<const float4*>(whh + (size_t)(2 * H + tid) * H);
    const float4* h4 = reinterpret_cast<const float4*>(sh);
    for (int k = 0; k < 32; k++) {
      float4 x = h4[k];
      float4 a = rp[k], b = zp[k], cc = np[k];
      hr += x.x * a.x + x.y * a.y + x.z * a.z + x.w * a.w;
      hz += x.x * b.x + x.y * b.y + x.z * b.z + x.w * b.w;
      hn += x.x * cc.x + x.y * cc.y + x.z * cc.z + x.w * cc.w;
    }
  }
  float r = sigm(gr + hr), z = sigm(gz + hz), nn = tanhf(gn + r * hn);
  float val = (1.0f - z) * nn + z * sh[tid];
  red[tid] = val * val;
  __syncthreads();
  for (int s2 = 64; s2 > 0; s2 >>= 1) {
    if (tid < s2) red[tid] += red[tid + s2];
    __syncthreads();
  }
  float inv = 1.0f / fmaxf(sqrtf(red[0]), 1e-12f);
  outp[rel * H + tid] = val * inv;
}

// ===========================================================================
// ConvTransE front — split-K GEMM. Block = 8 queries x 8 channels (K=1024).
// grid (NT/8, 4). Writes raw partial sums to Zp[ks][NT][H].
// ===========================================================================
__global__ __launch_bounds__(256) void conv_front(const float* __restrict__ fa,
                                                  const int* __restrict__ ia,
                                                  const float* __restrict__ fbm,
                                                  const int* __restrict__ ib,
                                                  const float* __restrict__ ck,
                                                  const float* __restrict__ ckb,
                                                  const float* __restrict__ fw,
                                                  float* __restrict__ Zp) {
  __shared__ float sx[8 * 2 * H];   // 8 KB : [q][i][p]
  __shared__ float sy[8 * 1024];    // 32 KB: [q][c*128+p]
  __shared__ float sck[48];
  __shared__ float sckb[8];
  int tid = threadIdx.x;
  int q0 = blockIdx.x * 8, ks = blockIdx.y;
  if (tid < 48) sck[tid] = ck[ks * 48 + tid];
  if (tid < 8)  sckb[tid] = ckb[ks * 8 + tid];
  // stage x rows
#pragma unroll
  for (int i = tid; i < 2048; i += 256) {
    int q = i >> 8, half = (i >> 7) & 1, p = i & 127;
    int node = (half ? ib : ia)[q0 + q];
    const float* srcp = (half ? fbm : fa) + (size_t)node * H + p;
    sx[i] = *srcp;
  }
  __syncthreads();
  // build y = relu(conv) for this channel slice
#pragma unroll
  for (int i = tid; i < 8192; i += 256) {
    int q = i >> 10, c = (i >> 7) & 7, p = i & 127;
    const float* xq = &sx[q * 256];
    float acc = sckb[c];
#pragma unroll
    for (int kk = 0; kk < 3; kk++) {
      int pos = p + kk - 1;
      if (pos >= 0 && pos < H)
        acc += xq[pos] * sck[c * 6 + kk] + xq[128 + pos] * sck[c * 6 + 3 + kk];
    }
    sy[i] = fmaxf(acc, 0.0f);
  }
  __syncthreads();
  // GEMM: o in {ot, ot+64}, queries {qg*2, qg*2+1}
  int ot = tid & 63, qg = tid >> 6;
  const float* w0p = fw + (size_t)ot * 4096 + ks * 1024;
  const float* w1p = fw + (size_t)(ot + 64) * 4096 + ks * 1024;
  const float* y0p = &sy[(qg * 2 + 0) * 1024];
  const float* y1p = &sy[(qg * 2 + 1) * 1024];
  float a00 = 0, a01 = 0, a10 = 0, a11 = 0;
  for (int j = 0; j < 1024; j += 4) {
    float4 w0 = *reinterpret_cast<const float4*>(w0p + j);
    float4 w1 = *reinterpret_cast<const float4*>(w1p + j);
    float4 y0 = *reinterpret_cast<const float4*>(y0p + j);
    float4 y1 = *reinterpret_cast<const float4*>(y1p + j);
    a00 += y0.x * w0.x + y0.y * w0.y + y0.z * w0.z + y0.w * w0.w;
    a10 += y0.x * w1.x + y0.y * w1.y + y0.z * w1.z + y0.w * w1.w;
    a01 += y1.x * w0.x + y1.y * w0.y + y1.z * w0.z + y1.w * w0.w;
    a11 += y1.x * w1.x + y1.y * w1.y + y1.z * w1.z + y1.w * w1.w;
  }
  float* zb = Zp + (size_t)ks * NT * H;
  zb[(size_t)(q0 + qg * 2 + 0) * H + ot]      = a00;
  zb[(size_t)(q0 + qg * 2 + 0) * H + ot + 64] = a10;
  zb[(size_t)(q0 + qg * 2 + 1) * H + ot]      = a01;
  zb[(size_t)(q0 + qg * 2 + 1) * H + ot + 64] = a11;
}

__global__ __launch_bounds__(256) void conv_finalize(const float* __restrict__ Zp,
                                                     const float* __restrict__ fb,
                                                     float* __restrict__ Z) {
  int i = blockIdx.x * 256 + threadIdx.x;  // NT*H / 256
  int o = i & 127;
  float v = Zp[i] + Zp[NT * H + i] + Zp[2 * NT * H + i] + Zp[3 * NT * H + i] + fb[o];
  Z[i] = fmaxf(v, 0.0f);
}

// ---- logits: 128x128 tile, Kc=32, 8x8/thread -------------------------------
__global__ __launch_bounds__(256) void logits_gemm2(const float* __restrict__ Z,
                                                    const float* __restrict__ F,
                                                    float* __restrict__ out,
                                                    int M) {
  __shared__ float sZ[32 * H];
  __shared__ float sF[32 * H];
  int t = threadIdx.x;
  int bq = blockIdx.y * 128, bm = blockIdx.x * 128;
  int tx = t & 15, ty = t >> 4;
  float acc[8][8] = {};
  int qld = t & 127, kh = (t >> 7) * 16;
  int mld = bm + qld;
  if (mld >= M) mld = M - 1;
  for (int kc = 0; kc < H; kc += 32) {
    __syncthreads();
    const float* zr = Z + (size_t)(bq + qld) * H + kc + kh;
    const float* fr = F + (size_t)mld * H + kc + kh;
#pragma unroll
    for (int j = 0; j < 16; j += 4) {
      float4 v = *reinterpret_cast<const float4*>(zr + j);
      sZ[(kh + j + 0) * H + qld] = v.x;
      sZ[(kh + j + 1) * H + qld] = v.y;
      sZ[(kh + j + 2) * H + qld] = v.z;
      sZ[(kh + j + 3) * H + qld] = v.w;
      float4 f = *reinterpret_cast<const float4*>(fr + j);
      sF[(kh + j + 0) * H + qld] = f.x;
      sF[(kh + j + 1) * H + qld] = f.y;
      sF[(kh + j + 2) * H + qld] = f.z;
      sF[(kh + j + 3) * H + qld] = f.w;
    }
    __syncthreads();
    for (int k = 0; k < 32; k++) {
      float4 za = *reinterpret_cast<const float4*>(&sZ[k * H + ty * 8]);
      float4 zb = *reinterpret_cast<const float4*>(&sZ[k * H + ty * 8 + 4]);
      float4 fa = *reinterpret_cast<const float4*>(&sF[k * H + tx * 8]);
      float4 fbv = *reinterpret_cast<const float4*>(&sF[k * H + tx * 8 + 4]);
      float zq[8] = {za.x, za.y, za.z, za.w, zb.x, zb.y, zb.z, zb.w};
      float fm[8] = {fa.x, fa.y, fa.z, fa.w, fbv.x, fbv.y, fbv.z, fbv.w};
#pragma unroll
      for (int i = 0; i < 8; i++)
#pragma unroll
        for (int j = 0; j < 8; j++) acc[i][j] += zq[i] * fm[j];
    }
  }
  int m0 = bm + tx * 8;
  if (m0 >= M) return;
#pragma unroll
  for (int i = 0; i < 8; i++) {
    size_t row = (size_t)(bq + ty * 8 + i) * (size_t)M + m0;
    float4 o1 = {acc[i][0], acc[i][1], acc[i][2], acc[i][3]};
    float4 o2 = {acc[i][4], acc[i][5], acc[i][6], acc[i][7]};
    *reinterpret_cast<float4*>(&out[row]) = o1;
    *reinterpret_cast<float4*>(&out[row + 4]) = o2;
  }
}

}  // namespace

extern "C" void kernel_launch(void* const* d_in, const int* in_sizes, int n_in,
                              void* d_out, int out_size, void* d_ws, size_t ws_size,
                              hipStream_t stream) {
  (void)in_sizes; (void)n_in; (void)out_size; (void)ws_size;
  const float* ent_embeds = (const float*)d_in[0];
  const float* rel_embeds = (const float*)d_in[1];
  const float* mmt_embed  = (const float*)d_in[2];
  const float* tc_w  = (const float*)d_in[3];
  const float* tc_b  = (const float*)d_in[4];
  const float* tc_pw = (const float*)d_in[5];
  const float* tc_pb = (const float*)d_in[6];
  const float* g1_wih = (const float*)d_in[7];
  const float* g1_whh = (const float*)d_in[8];
  const float* g1_bih = (const float*)d_in[9];
  const float* g1_bhh = (const float*)d_in[10];
  const float* l1_wih = (const float*)d_in[11];
  const float* l1_bih = (const float*)d_in[13];
  const float* l1_bhh = (const float*)d_in[14];
  const float* l2_wih = (const float*)d_in[15];
  const float* l2_bih = (const float*)d_in[17];
  const float* l2_bhh = (const float*)d_in[18];
  const float* lin_w = (const float*)d_in[19];
  const float* lin_b = (const float*)d_in[20];
  const float* rgcn_wn = (const float*)d_in[21];
  const float* rgcn_ws = (const float*)d_in[22];
  const float* rgcn_b  = (const float*)d_in[23];
  const float* oc_k  = (const float*)d_in[24];
  const float* oc_kb = (const float*)d_in[25];
  const float* oc_fw = (const float*)d_in[26];
  const float* oc_fb = (const float*)d_in[27];
  const float* rc_k  = (const float*)d_in[28];
  const float* rc_kb = (const float*)d_in[29];
  const float* rc_fw = (const float*)d_in[30];
  const float* rc_fb = (const float*)d_in[31];
  const int* src  = (const int*)d_in[32];
  const int* dst  = (const int*)d_in[33];
  const int* rid  = (const int*)d_in[34];
  const int* qsub = (const int*)d_in[35];
  const int* qrel = (const int*)d_in[36];
  const int* qobj = (const int*)d_in[37];

  float* out = (float*)d_out;
  float* ws  = (float*)d_ws;

  // ---- d_ws layout (floats) ----
  size_t off = 0;
  float* entF = ws + off; off += NEH;
  float* relhB[3] = {ws + off, ws + off + (size_t)NR * H, ws + off + 2 * (size_t)NR * H};
  off += 3 * (size_t)NR * H;
  float* rel_sum = ws + off; off += (size_t)NR * H;
  float* rcnt    = ws + off; off += NR;
  float* mmtbuf0 = ws + off; off += H;
  float* mmtbuf1 = ws + off; off += H;
  float* vbuf    = ws + off; off += H;
  float* MT      = ws + off; off += (size_t)H * H;
  float* WTlin   = ws + off; off += (size_t)H * H;
  float* Zo      = ws + off; off += (size_t)NT * H;
  float* Zr      = ws + off; off += (size_t)NT * H;
  float* Zpart   = ws + off; off += 4 * (size_t)NT * H;   // 2 MB, reused per front
  unsigned int* mask = (unsigned int*)(ws + off); off += (size_t)NR * MW;

  // ---- d_out as scratch: 4 rotating NE*H buffers + CSR ints in the tail ----
  float* B[4] = {out, out + NEH, out + 2 * NEH, out + 3 * NEH};
  int* itail   = (int*)(out + 4 * NEH);
  int* deg     = itail;
  int* rowptr  = itail + NE;
  int* wpos    = itail + 2 * NE + 1;
  int* elist   = itail + 3 * NE + 1;
  float* mmtb[2] = {mmtbuf0, mmtbuf1};

  norm_rows<<<(NE + 3) / 4, 256, 0, stream>>>(ent_embeds, B[0], NE);
  norm_rows<<<(NR + 3) / 4, 256, 0, stream>>>(rel_embeds, relhB[0], NR);
  copy_vec<<<1, 128, 0, stream>>>(mmt_embed, mmtbuf0, H);
  transpose128<<<64, 256, 0, stream>>>(lin_w, WTlin);

  int cur = 0, curRelh = 0;
  for (int t = 0; t < T; t++) {
    int fr[3], fi = 0;
    for (int b = 0; b < 4; b++) if (b != cur) fr[fi++] = b;
    int bX = fr[0], bG = fr[1], bY = fr[2];
    const int* s_t = src + (size_t)t * E;
    const int* d_t = dst + (size_t)t * E;
    const int* r_t = rid + (size_t)t * E;

    mmt_step<<<1, 128, 0, stream>>>(mmtb[t & 1], l1_wih, l1_bih, l1_bhh,
                                    l2_wih, l2_bih, l2_bhh, tc_w, tc_b,
                                    mmtb[(t + 1) & 1], vbuf);
    build_M<<<H, H, 0, stream>>>(vbuf, tc_pw, MT);
    gemm_bias<<<NE / 64, 256, 0, stream>>>(B[cur], MT, tc_pb, B[bX]);
    gemm_bias<<<NR / 64, 256, 0, stream>>>(relhB[curRelh], MT, tc_pb, relhB[2]);

    // edge prep: rel bitmask + dst degree (one pass)
    hipMemsetAsync(mask, 0, (size_t)NR * MW * 4, stream);
    hipMemsetAsync(deg, 0, (size_t)NE * 4, stream);
    edge_prep<<<(E + 255) / 256, 256, 0, stream>>>(s_t, d_t, r_t, mask, deg);

    hipMemsetAsync(rel_sum, 0, ((size_t)NR * H + NR) * 4, stream);
    agg_rel_sum<<<dim3(NR, 32), 128, 0, stream>>>(mask, B[bX], rel_sum, rcnt);
    int nextRelh = 1 - curRelh;
    rel_gru<<<NR, 128, 0, stream>>>(rel_sum, rcnt, rel_embeds, relhB[2],
                                    g1_wih, g1_whh, g1_bih, g1_bhh, relhB[nextRelh]);

    scan_deg<<<1, 1024, 0, stream>>>(deg, rowptr, wpos);
    edge_fill<<<(E + 255) / 256, 256, 0, stream>>>(d_t, wpos, elist);

    // RGCN layer 0
    rgcn_gather<<<NE / 2, 256, 0, stream>>>(B[bX], relhB[nextRelh], rowptr, elist, s_t, r_t, B[bG]);
    gemm_rgcn<<<NE / 32, 256, 0, stream>>>(B[bG], B[bX], rgcn_wn, rgcn_ws, rgcn_b, deg, B[bY], 0);
    // RGCN layer 1 (+ fused row-normalize)
    rgcn_gather<<<NE / 2, 256, 0, stream>>>(B[bY], relhB[nextRelh], rowptr, elist, s_t, r_t, B[bG]);
    gemm_rgcn<<<NE / 32, 256, 0, stream>>>(B[bG], B[bY], rgcn_wn + H * H, rgcn_ws + H * H,
                                           rgcn_b + H, deg, B[cur], 1);

    float* entDst = (t == T - 1) ? entF : B[bY];
    gemm_update<<<NE / 64, 256, 0, stream>>>(B[bX], WTlin, lin_b, B[cur], entDst);

    cur = bY;
    curRelh = nextRelh;
  }

  float* relhF = relhB[curRelh];

  // ConvTransE fronts (split-K + finalize)
  conv_front<<<dim3(NT / 8, 4), 256, 0, stream>>>(entF, qsub, relhF, qrel, oc_k, oc_kb, oc_fw, Zpart);
  conv_finalize<<<NT * H / 256, 256, 0, stream>>>(Zpart, oc_fb, Zo);
  conv_front<<<dim3(NT / 8, 4), 256, 0, stream>>>(entF, qsub, entF, qobj, rc_k, rc_kb, rc_fw, Zpart);
  conv_finalize<<<NT * H / 256, 256, 0, stream>>>(Zpart, rc_fb, Zr);

  // logits
  logits_gemm2<<<dim3((NE + 127) / 128, NT / 128), 256, 0, stream>>>(Zo, entF, out, NE);
  logits_gemm2<<<dim3(NR / 128, NT / 128), 256, 0, stream>>>(Zr, relhF, out + (size_t)NT * NE, NR);
}